// Round 12
// baseline (211.690 us; speedup 1.0000x reference)
//
#include <hip/hip_runtime.h>

typedef unsigned short u16;
typedef unsigned int u32;
typedef __attribute__((ext_vector_type(8))) short bf16x8;
typedef __attribute__((ext_vector_type(4))) short bf16x4;
typedef __attribute__((ext_vector_type(4))) float f32x4;
typedef __attribute__((ext_vector_type(16))) float f32x16;

__device__ __forceinline__ float b2f(u16 b){ u32 u = ((u32)b)<<16; float f; __builtin_memcpy(&f,&u,4); return f; }
__device__ __forceinline__ u16 f2b(float f){ u32 u; __builtin_memcpy(&u,&f,4); u32 r = (u + 0x7fffu + ((u>>16)&1u)) >> 16; return (u16)r; }
__device__ __forceinline__ u32 cvtpk(float lo, float hi){ u32 r; asm("v_cvt_pk_bf16_f32 %0, %1, %2" : "=v"(r) : "v"(lo), "v"(hi)); return r; }
__device__ __forceinline__ void pswap(u32 &a, u32 &b){ asm("v_permlane32_swap_b32 %0, %1" : "+v"(a), "+v"(b)); }
__device__ __forceinline__ void gload16(const u16* g, u16* l){
  __builtin_amdgcn_global_load_lds((const __attribute__((address_space(1))) void*)g,
                                   (__attribute__((address_space(3))) void*)l, 16, 0, 0);
}

// ---------------- fused prep: converts + weight transposes + degree count ----------------
// deg is zeroed by hipMemsetAsync BEFORE this kernel (init+count in one grid = block race, R3 failure).
__device__ __forceinline__ void conv_body(const float* __restrict__ in, u16* __restrict__ out, int b, int n){
  int i = (b*256 + threadIdx.x)*4;
  if (i + 3 < n){
    float4 v = *(const float4*)(in + i);
    bf16x4 o;
    o[0]=(short)f2b(v.x); o[1]=(short)f2b(v.y); o[2]=(short)f2b(v.z); o[3]=(short)f2b(v.w);
    *(bf16x4*)(out + i) = o;
  } else {
    for (; i<n; ++i) out[i]=f2b(in[i]);
  }
}
__global__ __launch_bounds__(256) void prep_k(const float* __restrict__ x, const float* __restrict__ inw,
    const float* __restrict__ outw, const float* __restrict__ W1, const float* __restrict__ W2,
    const float* __restrict__ Wc, const int* __restrict__ dst, int E,
    u16* __restrict__ Xb, u16* __restrict__ inWb, u16* __restrict__ outWb,
    u16* __restrict__ W1T, u16* __restrict__ W2T, u16* __restrict__ WcT, int* __restrict__ deg){
  __shared__ float tile[32][33];
  int b = blockIdx.x;
  if (b < 3072){ conv_body(x, Xb, b, 4096*768); return; }
  if (b < 3840){ conv_body(inw, inWb, b-3072, 1536*512); return; }
  if (b < 4096){ conv_body(outw, outWb, b-3840, 512*512); return; }
  if (b < 4752){
    const float* in; u16* out; int R, C, bx, by;
    if (b < 4480){ in=W1; out=W1T; R=768; C=512; int lb=b-4096; bx=lb&15; by=lb>>4; }
    else if (b < 4736){ in=W2; out=W2T; R=512; C=512; int lb=b-4480; bx=lb&15; by=lb>>4; }
    else { in=Wc; out=WcT; R=512; C=32; bx=0; by=b-4736; }
    int tx = threadIdx.x & 31, ty = threadIdx.x >> 5;
    int c0 = bx*32, r0 = by*32;
    #pragma unroll
    for (int k=0;k<4;++k){
      int r = r0 + ty + k*8, c = c0 + tx;
      if (r < R && c < C) tile[ty+k*8][tx] = in[(size_t)r*C + c];
    }
    __syncthreads();
    #pragma unroll
    for (int k=0;k<4;++k){
      int c = c0 + ty + k*8, r = r0 + tx;
      if (r < R && c < C) out[(size_t)c*R + r] = f2b(tile[tx][ty+k*8]);
    }
    return;
  }
  int e = (b-4752)*256 + threadIdx.x;
  if (e < E) atomicAdd(&deg[dst[e]], 1);
}

__global__ __launch_bounds__(256) void scan_k(const int* __restrict__ deg, int* __restrict__ row_ptr,
                                              int* __restrict__ cursor, float* __restrict__ dinv){
  __shared__ int lds[256];
  int t = threadIdx.x;
  int base = t*16;
  int cnt[16]; int s = 0;
  #pragma unroll
  for (int k=0;k<16;++k){
    int d = deg[base+k] + 1;      // +1 self-loop (deg holds edge count only)
    cnt[k] = d - 1;
    s += d - 1;
    dinv[base+k] = 1.0f / sqrtf((float)d);
  }
  lds[t] = s; __syncthreads();
  for (int o=1;o<256;o<<=1){
    int v = (t>=o) ? lds[t-o] : 0;
    __syncthreads();
    lds[t] += v;
    __syncthreads();
  }
  int run = lds[t] - s;
  #pragma unroll
  for (int k=0;k<16;++k){ row_ptr[base+k] = run; cursor[base+k] = run; run += cnt[k]; }
  if (t == 255) row_ptr[4096] = run;
}
__global__ __launch_bounds__(256) void scatter_k(const int* __restrict__ src, const int* __restrict__ dst,
                                                 int* __restrict__ cursor, int* __restrict__ srcl, int E){
  int e = blockIdx.x*256 + threadIdx.x;
  if (e < E){
    int d = dst[e];
    int pos = atomicAdd(&cursor[d], 1);
    srcl[pos] = src[e];
  }
}

// ---------------- GCN aggregation: 64 threads/node, bf16x8 (16B/lane) gather, 4-edge ILP ----------------
__global__ __launch_bounds__(64) void aggregate_k(const u16* __restrict__ H, const float* __restrict__ dinv,
                                                  const int* __restrict__ rp, const int* __restrict__ srcl,
                                                  const float* __restrict__ bias, u16* __restrict__ out){
  const int i = blockIdx.x, t = threadIdx.x;
  const float di = dinv[i];
  float a[8];
  {
    bf16x8 hv = *(const bf16x8*)(H + (size_t)i*512 + t*8);
    float wself = di*di;
    #pragma unroll
    for (int j=0;j<8;++j) a[j] = b2f((u16)hv[j])*wself;
  }
  int e0 = rp[i], e1 = rp[i+1];
  int e = e0;
  for (; e+3 < e1; e += 4){
    int s0 = srcl[e], s1 = srcl[e+1], s2 = srcl[e+2], s3 = srcl[e+3];
    float w0 = dinv[s0]*di, w1 = dinv[s1]*di, w2 = dinv[s2]*di, w3 = dinv[s3]*di;
    bf16x8 v0 = *(const bf16x8*)(H + (size_t)s0*512 + t*8);
    bf16x8 v1 = *(const bf16x8*)(H + (size_t)s1*512 + t*8);
    bf16x8 v2 = *(const bf16x8*)(H + (size_t)s2*512 + t*8);
    bf16x8 v3 = *(const bf16x8*)(H + (size_t)s3*512 + t*8);
    #pragma unroll
    for (int j=0;j<8;++j){
      a[j] += b2f((u16)v0[j])*w0 + b2f((u16)v1[j])*w1 + b2f((u16)v2[j])*w2 + b2f((u16)v3[j])*w3;
    }
  }
  for (; e < e1; ++e){
    int s = srcl[e];
    float w = dinv[s]*di;
    bf16x8 v = *(const bf16x8*)(H + (size_t)s*512 + t*8);
    #pragma unroll
    for (int j=0;j<8;++j) a[j] += b2f((u16)v[j])*w;
  }
  bf16x8 o;
  #pragma unroll
  for (int j=0;j<8;++j){
    float v = fmaxf(a[j] + bias[t*8+j], 0.f);
    o[j] = (short)f2b(v);
  }
  *(bf16x8*)(out + (size_t)i*512 + t*8) = o;
}

// ---------------- GEMM: C[M,N] = A[M,K] * B[N,K]^T, global_load_lds staging ----------------
// BM=64 tiles (2+ blocks/CU for N=512 grids); qkv uses BN=128/WN=64 (8 MFMA per 6 frag-reads).
template<int BM,int BN,int WM,int WN,bool BIAS,bool RESID,bool RELU,bool OUTBF,bool QKV>
__global__ __launch_bounds__(256) void gemm_abt_k(
    const u16* __restrict__ A, const u16* __restrict__ B,
    const float* __restrict__ bias, const u16* __restrict__ resid,
    u16* __restrict__ vt, void* __restrict__ Cp, int M, int N, int K)
{
  constexpr int BK = 64;
  constexpr int AISS = (BM*BK)/(256*8);
  constexpr int BISS = (BN*BK)/(256*8);
  constexpr int WC = BN/WN;
  constexpr int FM = WM/16, FN = WN/16;
  constexpr float QS = 0.088388347648318447f * 1.4426950408889634f;  // 1/sqrt(128) * log2(e)
  __shared__ u16 As[BM*BK];
  __shared__ u16 Bs[BN*BK];
  const int tid = threadIdx.x;
  const int wv = tid>>6, ln = tid&63;
  const int l15 = ln&15, l4 = ln>>4;
  const int wm = wv / WC, wn = wv % WC;
  const int bm0 = blockIdx.x*BM, bn0 = blockIdx.y*BN;
  const int arow = tid>>3;
  const int acol = (tid&7)*8;
  f32x4 acc[FM][FN];
  #pragma unroll
  for (int a=0;a<FM;++a)
    #pragma unroll
    for (int b=0;b<FN;++b) acc[a][b] = f32x4{0.f,0.f,0.f,0.f};
  for (int kt=0; kt<K; kt+=BK){
    #pragma unroll
    for (int i=0;i<AISS;++i) gload16(A + (size_t)(bm0 + i*32 + arow)*K + kt + acol, &As[i*2048 + wv*512]);
    #pragma unroll
    for (int i=0;i<BISS;++i) gload16(B + (size_t)(bn0 + i*32 + arow)*K + kt + acol, &Bs[i*2048 + wv*512]);
    __syncthreads();
    #pragma unroll
    for (int kc=0;kc<2;++kc){
      bf16x8 af[FM], bfr[FN];
      #pragma unroll
      for (int a=0;a<FM;++a) af[a] = *(const bf16x8*)(&As[(wm*WM + a*16 + l15)*BK + kc*32 + l4*8]);
      #pragma unroll
      for (int b=0;b<FN;++b) bfr[b] = *(const bf16x8*)(&Bs[(wn*WN + b*16 + l15)*BK + kc*32 + l4*8]);
      #pragma unroll
      for (int a=0;a<FM;++a)
        #pragma unroll
        for (int b=0;b<FN;++b)
          acc[a][b] = __builtin_amdgcn_mfma_f32_16x16x32_bf16(af[a], bfr[b], acc[a][b], 0,0,0);
    }
    __syncthreads();
  }
  #pragma unroll
  for (int a=0;a<FM;++a)
    #pragma unroll
    for (int b=0;b<FN;++b){
      int r0 = bm0 + wm*WM + a*16 + l4*4;
      int c  = bn0 + wn*WN + b*16 + l15;
      if constexpr (QKV){
        float v0 = acc[a][b][0] + bias[c];
        float v1 = acc[a][b][1] + bias[c];
        float v2 = acc[a][b][2] + bias[c];
        float v3 = acc[a][b][3] + bias[c];
        if (c >= 1024){
          bf16x4 pk; pk[0]=(short)f2b(v0); pk[1]=(short)f2b(v1); pk[2]=(short)f2b(v2); pk[3]=(short)f2b(v3);
          *(bf16x4*)(vt + (size_t)(c-1024)*4096 + r0) = pk;
        } else {
          float s = (c < 512) ? QS : 1.0f;
          u16* o = (u16*)Cp;
          o[(size_t)(r0+0)*N + c] = f2b(v0*s);
          o[(size_t)(r0+1)*N + c] = f2b(v1*s);
          o[(size_t)(r0+2)*N + c] = f2b(v2*s);
          o[(size_t)(r0+3)*N + c] = f2b(v3*s);
        }
      } else {
        #pragma unroll
        for (int j=0;j<4;++j){
          int r = r0 + j;
          float v = acc[a][b][j];
          if (BIAS)  v += bias[c];
          if (RESID) v += b2f(resid[(size_t)r*N + c]);
          if (RELU)  v = fmaxf(v, 0.f);
          if (OUTBF) ((u16*)Cp)[(size_t)r*N + c] = f2b(v);
          else       ((float*)Cp)[(size_t)r*N + c] = v;
        }
      }
    }
}

// ---------------- flash attention v5: 64 q-rows/wave + 8-way split = ratio AND TLP ----------------
// R11 lesson: 64 q-rows/wave cut LDS ops 30% but 1 block/CU (1 wave/SIMD) left it latency-bound.
// 8 splits -> grid (16,4,8) = 512 blocks = exactly 2/CU, ONE residency round (R5's 1024 = 2 rounds
// was the tail problem, not split count). VGPR 204 <= 256 so 2 waves/SIMD fit: (256,2) declared.
// bf16 partials keep Opart at 33.5MB (same HBM traffic as R10's 4-split f32). Vs rows span 256B.
__global__ __launch_bounds__(256,2) void attn_k(const u16* __restrict__ qkv, const u16* __restrict__ vtg,
                                                u16* __restrict__ Op, float* __restrict__ Lp){
  __shared__ u16 Ks[64*128];    // 64 kv rows x 256B, XOR-swz (row&15)<<4
  __shared__ u16 Vs[128*128];   // 128 d rows x 256B, XOR-swz (row&15)<<4
  const int head = blockIdx.y, split = blockIdx.z;
  const int qbase = blockIdx.x*256 + (threadIdx.x>>6)*64;
  const int tid = threadIdx.x, wv = tid>>6, ln = tid&63;
  const int l31 = ln&31, hi = ln>>5;
  bf16x8 qfA[8], qfB[8];
  {
    const u16* qp = qkv + (size_t)(qbase + l31)*1536 + head*128 + hi*8;
    #pragma unroll
    for (int kk=0;kk<8;++kk){ qfA[kk] = *(const bf16x8*)(qp + kk*16); qfB[kk] = *(const bf16x8*)(qp + 32*1536 + kk*16); }
  }
  f32x16 accA[4], accB[4];
  #pragma unroll
  for (int d=0;d<4;++d)
    #pragma unroll
    for (int r=0;r<16;++r){ accA[d][r] = 0.f; accB[d][r] = 0.f; }
  float lA = 0.f, lB = 0.f;
  const int kR = ln, kG = wv*4;
  const int vR = tid>>1, vG = (tid&1)*4;
  const u16* kbase = qkv + 512 + (size_t)head*128;
  const u16* vbase = vtg + (size_t)(head*128 + vR)*4096;
  const int kv00 = split*512;
  bf16x8 kreg[4], vreg[4];
  #pragma unroll
  for (int i=0;i<4;++i){
    kreg[i] = *(const bf16x8*)(kbase + (size_t)(kv00 + kR)*1536 + (kG+i)*8);
    vreg[i] = *(const bf16x8*)(vbase + kv00 + (vG+i)*8);
  }
  union PU { u32 w[4]; bf16x8 v; };
  for (int it=0; it<8; ++it){
    #pragma unroll
    for (int i=0;i<4;++i){
      *(bf16x8*)((char*)Ks + kR*256 + (((kG+i)*16) ^ ((kR&15)<<4))) = kreg[i];
      *(bf16x8*)((char*)Vs + vR*256 + (((vG+i)*16) ^ ((vR&15)<<4))) = vreg[i];
    }
    __syncthreads();
    if (it < 7){
      int nb = kv00 + (it+1)*64;
      #pragma unroll
      for (int i=0;i<4;++i){
        kreg[i] = *(const bf16x8*)(kbase + (size_t)(nb + kR)*1536 + (kG+i)*8);
        vreg[i] = *(const bf16x8*)(vbase + nb + (vG+i)*8);
      }
    }
    PU paA[4], paB[4];
    // ---- q-block A: QK^T + softmax ----
    {
      f32x16 s0, s1;
      #pragma unroll
      for (int r=0;r<16;++r){ s0[r]=0.f; s1[r]=0.f; }
      #pragma unroll
      for (int kk=0;kk<8;++kk){
        int r0 = l31, r1 = 32 + l31;
        bf16x8 k0 = *(const bf16x8*)((char*)Ks + r0*256 + ((kk*32 + hi*16) ^ ((r0&15)<<4)));
        bf16x8 k1 = *(const bf16x8*)((char*)Ks + r1*256 + ((kk*32 + hi*16) ^ ((r1&15)<<4)));
        s0 = __builtin_amdgcn_mfma_f32_32x32x16_bf16(k0, qfA[kk], s0, 0,0,0);
        s1 = __builtin_amdgcn_mfma_f32_32x32x16_bf16(k1, qfA[kk], s1, 0,0,0);
      }
      #pragma unroll
      for (int g=0; g<2; ++g){
        float p[16];
        #pragma unroll
        for (int r=0;r<16;++r){ float sv = g ? s1[r] : s0[r]; p[r] = __builtin_amdgcn_exp2f(sv); lA += p[r]; }
        u32 c0=cvtpk(p[0],p[1]), c1=cvtpk(p[2],p[3]), c2=cvtpk(p[4],p[5]), c3=cvtpk(p[6],p[7]);
        u32 c4=cvtpk(p[8],p[9]), c5=cvtpk(p[10],p[11]), c6=cvtpk(p[12],p[13]), c7=cvtpk(p[14],p[15]);
        pswap(c0,c2); pswap(c1,c3); pswap(c4,c6); pswap(c5,c7);
        paA[g*2+0].w[0]=c0; paA[g*2+0].w[1]=c1; paA[g*2+0].w[2]=c2; paA[g*2+0].w[3]=c3;
        paA[g*2+1].w[0]=c4; paA[g*2+1].w[1]=c5; paA[g*2+1].w[2]=c6; paA[g*2+1].w[3]=c7;
      }
    }
    // ---- q-block B: QK^T + softmax (K-frags re-read) ----
    {
      f32x16 s0, s1;
      #pragma unroll
      for (int r=0;r<16;++r){ s0[r]=0.f; s1[r]=0.f; }
      #pragma unroll
      for (int kk=0;kk<8;++kk){
        int r0 = l31, r1 = 32 + l31;
        bf16x8 k0 = *(const bf16x8*)((char*)Ks + r0*256 + ((kk*32 + hi*16) ^ ((r0&15)<<4)));
        bf16x8 k1 = *(const bf16x8*)((char*)Ks + r1*256 + ((kk*32 + hi*16) ^ ((r1&15)<<4)));
        s0 = __builtin_amdgcn_mfma_f32_32x32x16_bf16(k0, qfB[kk], s0, 0,0,0);
        s1 = __builtin_amdgcn_mfma_f32_32x32x16_bf16(k1, qfB[kk], s1, 0,0,0);
      }
      #pragma unroll
      for (int g=0; g<2; ++g){
        float p[16];
        #pragma unroll
        for (int r=0;r<16;++r){ float sv = g ? s1[r] : s0[r]; p[r] = __builtin_amdgcn_exp2f(sv); lB += p[r]; }
        u32 c0=cvtpk(p[0],p[1]), c1=cvtpk(p[2],p[3]), c2=cvtpk(p[4],p[5]), c3=cvtpk(p[6],p[7]);
        u32 c4=cvtpk(p[8],p[9]), c5=cvtpk(p[10],p[11]), c6=cvtpk(p[12],p[13]), c7=cvtpk(p[14],p[15]);
        pswap(c0,c2); pswap(c1,c3); pswap(c4,c6); pswap(c5,c7);
        paB[g*2+0].w[0]=c0; paB[g*2+0].w[1]=c1; paB[g*2+0].w[2]=c2; paB[g*2+0].w[3]=c3;
        paB[g*2+1].w[0]=c4; paB[g*2+1].w[1]=c5; paB[g*2+1].w[2]=c6; paB[g*2+1].w[3]=c7;
      }
    }
    // ---- PV: each V-frag read feeds both q-blocks (2 MFMA per read) ----
    #pragma unroll
    for (int dg=0;dg<4;++dg){
      int row = dg*32 + l31;
      #pragma unroll
      for (int kvf=0;kvf<4;++kvf){
        bf16x8 vf = *(const bf16x8*)((char*)Vs + row*256 + ((kvf*32 + hi*16) ^ ((row&15)<<4)));
        accA[dg] = __builtin_amdgcn_mfma_f32_32x32x16_bf16(paA[kvf].v, vf, accA[dg], 0,0,0);
        accB[dg] = __builtin_amdgcn_mfma_f32_32x32x16_bf16(paB[kvf].v, vf, accB[dg], 0,0,0);
      }
    }
    __syncthreads();
  }
  float ltA = lA + __shfl_xor(lA, 32, 64);
  float ltB = lB + __shfl_xor(lB, 32, 64);
  if (hi == 0){
    Lp[split*4096 + qbase + l31] = ltA;
    Lp[split*4096 + qbase + 32 + l31] = ltB;
  }
  #pragma unroll
  for (int dg=0;dg<4;++dg){
    #pragma unroll
    for (int r=0;r<16;++r){
      int qo = (r&3) + ((r>>2)<<3) + hi*4;
      Op[((size_t)split*4096 + qbase + qo)*512 + head*128 + dg*32 + l31] = f2b(accA[dg][r]);
      Op[((size_t)split*4096 + qbase + 32 + qo)*512 + head*128 + dg*32 + l31] = f2b(accB[dg][r]);
    }
  }
}

// ---------------- combine bf16 partials (8 splits) -> oatt ----------------
__global__ __launch_bounds__(256) void combine_k(const u16* __restrict__ Op, const float* __restrict__ Lp,
                                                 u16* __restrict__ oatt){
  int idx = blockIdx.x*256 + threadIdx.x;   // 4096*64
  int n = idx >> 6, c8 = (idx & 63) << 3;
  float l = 0.f;
  #pragma unroll
  for (int s=0;s<8;++s) l += Lp[s*4096+n];
  float inv = 1.0f/l;
  float acc[8] = {0,0,0,0,0,0,0,0};
  #pragma unroll
  for (int s=0;s<8;++s){
    bf16x8 v = *(const bf16x8*)(Op + ((size_t)(s*4096+n))*512 + c8);
    #pragma unroll
    for (int j=0;j<8;++j) acc[j] += b2f((u16)v[j]);
  }
  bf16x8 o;
  #pragma unroll
  for (int j=0;j<8;++j) o[j] = (short)f2b(acc[j]*inv);
  *(bf16x8*)(oatt + (size_t)n*512 + c8) = o;
}

// ---------------- launch ----------------
extern "C" void kernel_launch(void* const* d_in, const int* in_sizes, int n_in,
                              void* d_out, int out_size, void* d_ws, size_t ws_size,
                              hipStream_t stream) {
  (void)n_in; (void)out_size; (void)ws_size;
  const float* x    = (const float*)d_in[0];
  const int*   ei   = (const int*)d_in[1];
  const float* W1   = (const float*)d_in[2];
  const float* b1   = (const float*)d_in[3];
  const float* inw  = (const float*)d_in[4];
  const float* inb  = (const float*)d_in[5];
  const float* outw = (const float*)d_in[6];
  const float* outb = (const float*)d_in[7];
  const float* W2   = (const float*)d_in[8];
  const float* b2   = (const float*)d_in[9];
  const float* Wc   = (const float*)d_in[10];
  const float* bc   = (const float*)d_in[11];
  float* out = (float*)d_out;
  const int E = in_sizes[1] / 2;
  const int* srcp = ei;
  const int* dstp = ei + E;

  char* base = (char*)d_ws;
  size_t off = 0;
  auto alloc = [&](size_t bytes)->void*{
    void* p = base + off;
    off = (off + bytes + 255) & ~((size_t)255);
    return p;
  };
  u16* Xb    = (u16*)alloc((size_t)4096*768*2);
  u16* W1T   = (u16*)alloc((size_t)512*768*2);
  u16* inWb  = (u16*)alloc((size_t)1536*512*2);
  u16* outWb = (u16*)alloc((size_t)512*512*2);
  u16* W2T   = (u16*)alloc((size_t)512*512*2);
  u16* WcT   = (u16*)alloc((size_t)32*512*2);
  u16* Hpre  = (u16*)alloc((size_t)4096*512*2);
  u16* h1    = (u16*)alloc((size_t)4096*512*2);
  u16* qkvb  = (u16*)alloc((size_t)4096*1536*2);
  u16* vtg   = (u16*)alloc((size_t)512*4096*2);
  u16* oatt  = (u16*)alloc((size_t)4096*512*2);
  u16* h2    = (u16*)alloc((size_t)4096*512*2);
  u16* h3    = (u16*)alloc((size_t)4096*512*2);
  u16* Opart = (u16*)alloc((size_t)8*4096*512*2);
  float* Lpart = (float*)alloc((size_t)8*4096*4);
  int*   deg  = (int*)alloc(4096*4);
  float* dinv = (float*)alloc(4096*4);
  int*   rowp = (int*)alloc(4097*4);
  int*   curs = (int*)alloc(4096*4);
  int*   srcl = (int*)alloc((size_t)E*4);

  // deg = 0 (stream-ordered; avoids the R3 init/count same-grid race), then fused prep
  hipMemsetAsync(deg, 0, 4096*sizeof(int), stream);
  int degBlocks = (E + 255)/256;
  prep_k<<<4752 + degBlocks, 256, 0, stream>>>(x, inw, outw, W1, W2, Wc, dstp, E,
                                               Xb, inWb, outWb, W1T, W2T, WcT, deg);
  scan_k<<<1,256,0,stream>>>(deg, rowp, curs, dinv);
  scatter_k<<<(E+255)/256,256,0,stream>>>(srcp, dstp, curs, srcl, E);

  // layer 1
  gemm_abt_k<64,64,32,32,false,false,false,true,false><<<dim3(64,8),256,0,stream>>>(Xb, W1T, nullptr, nullptr, nullptr, Hpre, 4096, 512, 768);
  aggregate_k<<<4096,64,0,stream>>>(Hpre, dinv, rowp, srcl, b1, h1);

  // MHA (qkv: 64x128 tile, grid 64x12 = 768 = 3 blocks/CU)
  gemm_abt_k<64,128,32,64,true,false,false,true,true><<<dim3(64,12),256,0,stream>>>(h1, inWb, inb, nullptr, vtg, qkvb, 4096, 1536, 512);
  attn_k<<<dim3(16,4,8),256,0,stream>>>(qkvb, vtg, Opart, Lpart);
  combine_k<<<1024,256,0,stream>>>(Opart, Lpart, oatt);
  gemm_abt_k<64,64,32,32,true,true,false,true,false><<<dim3(64,8),256,0,stream>>>(oatt, outWb, outb, h1, nullptr, h2, 4096, 512, 512);

  // layer 2
  gemm_abt_k<64,64,32,32,false,false,false,true,false><<<dim3(64,8),256,0,stream>>>(h2, W2T, nullptr, nullptr, nullptr, Hpre, 4096, 512, 512);
  aggregate_k<<<4096,64,0,stream>>>(Hpre, dinv, rowp, srcl, b2, h3);

  // classifier -> f32 out
  gemm_abt_k<64,32,16,32,true,false,false,false,false><<<dim3(64,1),256,0,stream>>>(h3, WcT, bc, nullptr, nullptr, out, 4096, 32, 512);
}

// Round 13
// 169.882 us; speedup vs baseline: 1.2461x; 1.2461x over previous
//
#include <hip/hip_runtime.h>

typedef unsigned short u16;
typedef unsigned int u32;
typedef __attribute__((ext_vector_type(8))) short bf16x8;
typedef __attribute__((ext_vector_type(4))) short bf16x4;
typedef __attribute__((ext_vector_type(4))) float f32x4;
typedef __attribute__((ext_vector_type(16))) float f32x16;

__device__ __forceinline__ float b2f(u16 b){ u32 u = ((u32)b)<<16; float f; __builtin_memcpy(&f,&u,4); return f; }
__device__ __forceinline__ u16 f2b(float f){ u32 u; __builtin_memcpy(&u,&f,4); u32 r = (u + 0x7fffu + ((u>>16)&1u)) >> 16; return (u16)r; }
__device__ __forceinline__ u32 cvtpk(float lo, float hi){ u32 r; asm("v_cvt_pk_bf16_f32 %0, %1, %2" : "=v"(r) : "v"(lo), "v"(hi)); return r; }
__device__ __forceinline__ void pswap(u32 &a, u32 &b){ asm("v_permlane32_swap_b32 %0, %1" : "+v"(a), "+v"(b)); }
__device__ __forceinline__ void gload16(const u16* g, u16* l){
  __builtin_amdgcn_global_load_lds((const __attribute__((address_space(1))) void*)g,
                                   (__attribute__((address_space(3))) void*)l, 16, 0, 0);
}

// ---------------- fused prep: converts + weight transposes + degree count ----------------
// deg is zeroed by hipMemsetAsync BEFORE this kernel (init+count in one grid = block race, R3 failure).
__device__ __forceinline__ void conv_body(const float* __restrict__ in, u16* __restrict__ out, int b, int n){
  int i = (b*256 + threadIdx.x)*4;
  if (i + 3 < n){
    float4 v = *(const float4*)(in + i);
    bf16x4 o;
    o[0]=(short)f2b(v.x); o[1]=(short)f2b(v.y); o[2]=(short)f2b(v.z); o[3]=(short)f2b(v.w);
    *(bf16x4*)(out + i) = o;
  } else {
    for (; i<n; ++i) out[i]=f2b(in[i]);
  }
}
__global__ __launch_bounds__(256) void prep_k(const float* __restrict__ x, const float* __restrict__ inw,
    const float* __restrict__ outw, const float* __restrict__ W1, const float* __restrict__ W2,
    const float* __restrict__ Wc, const int* __restrict__ dst, int E,
    u16* __restrict__ Xb, u16* __restrict__ inWb, u16* __restrict__ outWb,
    u16* __restrict__ W1T, u16* __restrict__ W2T, u16* __restrict__ WcT, int* __restrict__ deg){
  __shared__ float tile[32][33];
  int b = blockIdx.x;
  if (b < 3072){ conv_body(x, Xb, b, 4096*768); return; }
  if (b < 3840){ conv_body(inw, inWb, b-3072, 1536*512); return; }
  if (b < 4096){ conv_body(outw, outWb, b-3840, 512*512); return; }
  if (b < 4752){
    const float* in; u16* out; int R, C, bx, by;
    if (b < 4480){ in=W1; out=W1T; R=768; C=512; int lb=b-4096; bx=lb&15; by=lb>>4; }
    else if (b < 4736){ in=W2; out=W2T; R=512; C=512; int lb=b-4480; bx=lb&15; by=lb>>4; }
    else { in=Wc; out=WcT; R=512; C=32; bx=0; by=b-4736; }
    int tx = threadIdx.x & 31, ty = threadIdx.x >> 5;
    int c0 = bx*32, r0 = by*32;
    #pragma unroll
    for (int k=0;k<4;++k){
      int r = r0 + ty + k*8, c = c0 + tx;
      if (r < R && c < C) tile[ty+k*8][tx] = in[(size_t)r*C + c];
    }
    __syncthreads();
    #pragma unroll
    for (int k=0;k<4;++k){
      int c = c0 + ty + k*8, r = r0 + tx;
      if (r < R && c < C) out[(size_t)c*R + r] = f2b(tile[tx][ty+k*8]);
    }
    return;
  }
  int e = (b-4752)*256 + threadIdx.x;
  if (e < E) atomicAdd(&deg[dst[e]], 1);
}

__global__ __launch_bounds__(256) void scan_k(const int* __restrict__ deg, int* __restrict__ row_ptr,
                                              int* __restrict__ cursor, float* __restrict__ dinv){
  __shared__ int lds[256];
  int t = threadIdx.x;
  int base = t*16;
  int cnt[16]; int s = 0;
  #pragma unroll
  for (int k=0;k<16;++k){
    int d = deg[base+k] + 1;      // +1 self-loop (deg holds edge count only)
    cnt[k] = d - 1;
    s += d - 1;
    dinv[base+k] = 1.0f / sqrtf((float)d);
  }
  lds[t] = s; __syncthreads();
  for (int o=1;o<256;o<<=1){
    int v = (t>=o) ? lds[t-o] : 0;
    __syncthreads();
    lds[t] += v;
    __syncthreads();
  }
  int run = lds[t] - s;
  #pragma unroll
  for (int k=0;k<16;++k){ row_ptr[base+k] = run; cursor[base+k] = run; run += cnt[k]; }
  if (t == 255) row_ptr[4096] = run;
}
__global__ __launch_bounds__(256) void scatter_k(const int* __restrict__ src, const int* __restrict__ dst,
                                                 int* __restrict__ cursor, int* __restrict__ srcl, int E){
  int e = blockIdx.x*256 + threadIdx.x;
  if (e < E){
    int d = dst[e];
    int pos = atomicAdd(&cursor[d], 1);
    srcl[pos] = src[e];
  }
}

// ---------------- GCN aggregation: 64 threads/node, bf16x8 (16B/lane) gather, 4-edge ILP ----------------
__global__ __launch_bounds__(64) void aggregate_k(const u16* __restrict__ H, const float* __restrict__ dinv,
                                                  const int* __restrict__ rp, const int* __restrict__ srcl,
                                                  const float* __restrict__ bias, u16* __restrict__ out){
  const int i = blockIdx.x, t = threadIdx.x;
  const float di = dinv[i];
  float a[8];
  {
    bf16x8 hv = *(const bf16x8*)(H + (size_t)i*512 + t*8);
    float wself = di*di;
    #pragma unroll
    for (int j=0;j<8;++j) a[j] = b2f((u16)hv[j])*wself;
  }
  int e0 = rp[i], e1 = rp[i+1];
  int e = e0;
  for (; e+3 < e1; e += 4){
    int s0 = srcl[e], s1 = srcl[e+1], s2 = srcl[e+2], s3 = srcl[e+3];
    float w0 = dinv[s0]*di, w1 = dinv[s1]*di, w2 = dinv[s2]*di, w3 = dinv[s3]*di;
    bf16x8 v0 = *(const bf16x8*)(H + (size_t)s0*512 + t*8);
    bf16x8 v1 = *(const bf16x8*)(H + (size_t)s1*512 + t*8);
    bf16x8 v2 = *(const bf16x8*)(H + (size_t)s2*512 + t*8);
    bf16x8 v3 = *(const bf16x8*)(H + (size_t)s3*512 + t*8);
    #pragma unroll
    for (int j=0;j<8;++j){
      a[j] += b2f((u16)v0[j])*w0 + b2f((u16)v1[j])*w1 + b2f((u16)v2[j])*w2 + b2f((u16)v3[j])*w3;
    }
  }
  for (; e < e1; ++e){
    int s = srcl[e];
    float w = dinv[s]*di;
    bf16x8 v = *(const bf16x8*)(H + (size_t)s*512 + t*8);
    #pragma unroll
    for (int j=0;j<8;++j) a[j] += b2f((u16)v[j])*w;
  }
  bf16x8 o;
  #pragma unroll
  for (int j=0;j<8;++j){
    float v = fmaxf(a[j] + bias[t*8+j], 0.f);
    o[j] = (short)f2b(v);
  }
  *(bf16x8*)(out + (size_t)i*512 + t*8) = o;
}

// ---------------- GEMM: C[M,N] = A[M,K] * B[N,K]^T, global_load_lds staging ----------------
// BM=64 tiles (2+ blocks/CU for N=512 grids); qkv uses BN=128/WN=64 (8 MFMA per 6 frag-reads).
template<int BM,int BN,int WM,int WN,bool BIAS,bool RESID,bool RELU,bool OUTBF,bool QKV>
__global__ __launch_bounds__(256) void gemm_abt_k(
    const u16* __restrict__ A, const u16* __restrict__ B,
    const float* __restrict__ bias, const u16* __restrict__ resid,
    u16* __restrict__ vt, void* __restrict__ Cp, int M, int N, int K)
{
  constexpr int BK = 64;
  constexpr int AISS = (BM*BK)/(256*8);
  constexpr int BISS = (BN*BK)/(256*8);
  constexpr int WC = BN/WN;
  constexpr int FM = WM/16, FN = WN/16;
  constexpr float QS = 0.088388347648318447f * 1.4426950408889634f;  // 1/sqrt(128) * log2(e)
  __shared__ u16 As[BM*BK];
  __shared__ u16 Bs[BN*BK];
  const int tid = threadIdx.x;
  const int wv = tid>>6, ln = tid&63;
  const int l15 = ln&15, l4 = ln>>4;
  const int wm = wv / WC, wn = wv % WC;
  const int bm0 = blockIdx.x*BM, bn0 = blockIdx.y*BN;
  const int arow = tid>>3;
  const int acol = (tid&7)*8;
  f32x4 acc[FM][FN];
  #pragma unroll
  for (int a=0;a<FM;++a)
    #pragma unroll
    for (int b=0;b<FN;++b) acc[a][b] = f32x4{0.f,0.f,0.f,0.f};
  for (int kt=0; kt<K; kt+=BK){
    #pragma unroll
    for (int i=0;i<AISS;++i) gload16(A + (size_t)(bm0 + i*32 + arow)*K + kt + acol, &As[i*2048 + wv*512]);
    #pragma unroll
    for (int i=0;i<BISS;++i) gload16(B + (size_t)(bn0 + i*32 + arow)*K + kt + acol, &Bs[i*2048 + wv*512]);
    __syncthreads();
    #pragma unroll
    for (int kc=0;kc<2;++kc){
      bf16x8 af[FM], bfr[FN];
      #pragma unroll
      for (int a=0;a<FM;++a) af[a] = *(const bf16x8*)(&As[(wm*WM + a*16 + l15)*BK + kc*32 + l4*8]);
      #pragma unroll
      for (int b=0;b<FN;++b) bfr[b] = *(const bf16x8*)(&Bs[(wn*WN + b*16 + l15)*BK + kc*32 + l4*8]);
      #pragma unroll
      for (int a=0;a<FM;++a)
        #pragma unroll
        for (int b=0;b<FN;++b)
          acc[a][b] = __builtin_amdgcn_mfma_f32_16x16x32_bf16(af[a], bfr[b], acc[a][b], 0,0,0);
    }
    __syncthreads();
  }
  #pragma unroll
  for (int a=0;a<FM;++a)
    #pragma unroll
    for (int b=0;b<FN;++b){
      int r0 = bm0 + wm*WM + a*16 + l4*4;
      int c  = bn0 + wn*WN + b*16 + l15;
      if constexpr (QKV){
        float v0 = acc[a][b][0] + bias[c];
        float v1 = acc[a][b][1] + bias[c];
        float v2 = acc[a][b][2] + bias[c];
        float v3 = acc[a][b][3] + bias[c];
        if (c >= 1024){
          bf16x4 pk; pk[0]=(short)f2b(v0); pk[1]=(short)f2b(v1); pk[2]=(short)f2b(v2); pk[3]=(short)f2b(v3);
          *(bf16x4*)(vt + (size_t)(c-1024)*4096 + r0) = pk;
        } else {
          float s = (c < 512) ? QS : 1.0f;
          u16* o = (u16*)Cp;
          o[(size_t)(r0+0)*N + c] = f2b(v0*s);
          o[(size_t)(r0+1)*N + c] = f2b(v1*s);
          o[(size_t)(r0+2)*N + c] = f2b(v2*s);
          o[(size_t)(r0+3)*N + c] = f2b(v3*s);
        }
      } else {
        #pragma unroll
        for (int j=0;j<4;++j){
          int r = r0 + j;
          float v = acc[a][b][j];
          if (BIAS)  v += bias[c];
          if (RESID) v += b2f(resid[(size_t)r*N + c]);
          if (RELU)  v = fmaxf(v, 0.f);
          if (OUTBF) ((u16*)Cp)[(size_t)r*N + c] = f2b(v);
          else       ((float*)Cp)[(size_t)r*N + c] = v;
        }
      }
    }
}

// ---------------- flash attention v5b: 64 q-rows/wave + 8-way split, NO launch_bounds ----------------
// R12 failure: __launch_bounds__(256,2) capped arch VGPR at 128 (gfx950 empirical: (256,N) -> 256/N)
// -> spill storm. This kernel needs ~204 VGPR; WITHOUT any bound the allocator picks ~204, which
// naturally permits 2 blocks/CU (8 waves x 204 <= 2048 regs, 2 x 48KB <= 160KB LDS). grid 512 = 2/CU,
// one residency round: the R11 LDS:MFMA ratio win (448/512) finally gets TLP.
// bf16 partials (accuracy proven R6/R9). Vs rows span 256B (XOR swizzle needs bit-7).
__global__ __launch_bounds__(256) void attn_k(const u16* __restrict__ qkv, const u16* __restrict__ vtg,
                                              u16* __restrict__ Op, float* __restrict__ Lp){
  __shared__ u16 Ks[64*128];    // 64 kv rows x 256B, XOR-swz (row&15)<<4
  __shared__ u16 Vs[128*128];   // 128 d rows x 256B, XOR-swz (row&15)<<4
  const int head = blockIdx.y, split = blockIdx.z;
  const int qbase = blockIdx.x*256 + (threadIdx.x>>6)*64;
  const int tid = threadIdx.x, wv = tid>>6, ln = tid&63;
  const int l31 = ln&31, hi = ln>>5;
  bf16x8 qfA[8], qfB[8];
  {
    const u16* qp = qkv + (size_t)(qbase + l31)*1536 + head*128 + hi*8;
    #pragma unroll
    for (int kk=0;kk<8;++kk){ qfA[kk] = *(const bf16x8*)(qp + kk*16); qfB[kk] = *(const bf16x8*)(qp + 32*1536 + kk*16); }
  }
  f32x16 accA[4], accB[4];
  #pragma unroll
  for (int d=0;d<4;++d)
    #pragma unroll
    for (int r=0;r<16;++r){ accA[d][r] = 0.f; accB[d][r] = 0.f; }
  float lA = 0.f, lB = 0.f;
  const int kR = ln, kG = wv*4;
  const int vR = tid>>1, vG = (tid&1)*4;
  const u16* kbase = qkv + 512 + (size_t)head*128;
  const u16* vbase = vtg + (size_t)(head*128 + vR)*4096;
  const int kv00 = split*512;
  bf16x8 kreg[4], vreg[4];
  #pragma unroll
  for (int i=0;i<4;++i){
    kreg[i] = *(const bf16x8*)(kbase + (size_t)(kv00 + kR)*1536 + (kG+i)*8);
    vreg[i] = *(const bf16x8*)(vbase + kv00 + (vG+i)*8);
  }
  union PU { u32 w[4]; bf16x8 v; };
  for (int it=0; it<8; ++it){
    #pragma unroll
    for (int i=0;i<4;++i){
      *(bf16x8*)((char*)Ks + kR*256 + (((kG+i)*16) ^ ((kR&15)<<4))) = kreg[i];
      *(bf16x8*)((char*)Vs + vR*256 + (((vG+i)*16) ^ ((vR&15)<<4))) = vreg[i];
    }
    __syncthreads();
    if (it < 7){
      int nb = kv00 + (it+1)*64;
      #pragma unroll
      for (int i=0;i<4;++i){
        kreg[i] = *(const bf16x8*)(kbase + (size_t)(nb + kR)*1536 + (kG+i)*8);
        vreg[i] = *(const bf16x8*)(vbase + nb + (vG+i)*8);
      }
    }
    PU paA[4], paB[4];
    // ---- q-block A: QK^T + softmax ----
    {
      f32x16 s0, s1;
      #pragma unroll
      for (int r=0;r<16;++r){ s0[r]=0.f; s1[r]=0.f; }
      #pragma unroll
      for (int kk=0;kk<8;++kk){
        int r0 = l31, r1 = 32 + l31;
        bf16x8 k0 = *(const bf16x8*)((char*)Ks + r0*256 + ((kk*32 + hi*16) ^ ((r0&15)<<4)));
        bf16x8 k1 = *(const bf16x8*)((char*)Ks + r1*256 + ((kk*32 + hi*16) ^ ((r1&15)<<4)));
        s0 = __builtin_amdgcn_mfma_f32_32x32x16_bf16(k0, qfA[kk], s0, 0,0,0);
        s1 = __builtin_amdgcn_mfma_f32_32x32x16_bf16(k1, qfA[kk], s1, 0,0,0);
      }
      #pragma unroll
      for (int g=0; g<2; ++g){
        float p[16];
        #pragma unroll
        for (int r=0;r<16;++r){ float sv = g ? s1[r] : s0[r]; p[r] = __builtin_amdgcn_exp2f(sv); lA += p[r]; }
        u32 c0=cvtpk(p[0],p[1]), c1=cvtpk(p[2],p[3]), c2=cvtpk(p[4],p[5]), c3=cvtpk(p[6],p[7]);
        u32 c4=cvtpk(p[8],p[9]), c5=cvtpk(p[10],p[11]), c6=cvtpk(p[12],p[13]), c7=cvtpk(p[14],p[15]);
        pswap(c0,c2); pswap(c1,c3); pswap(c4,c6); pswap(c5,c7);
        paA[g*2+0].w[0]=c0; paA[g*2+0].w[1]=c1; paA[g*2+0].w[2]=c2; paA[g*2+0].w[3]=c3;
        paA[g*2+1].w[0]=c4; paA[g*2+1].w[1]=c5; paA[g*2+1].w[2]=c6; paA[g*2+1].w[3]=c7;
      }
    }
    // ---- q-block B: QK^T + softmax (K-frags re-read) ----
    {
      f32x16 s0, s1;
      #pragma unroll
      for (int r=0;r<16;++r){ s0[r]=0.f; s1[r]=0.f; }
      #pragma unroll
      for (int kk=0;kk<8;++kk){
        int r0 = l31, r1 = 32 + l31;
        bf16x8 k0 = *(const bf16x8*)((char*)Ks + r0*256 + ((kk*32 + hi*16) ^ ((r0&15)<<4)));
        bf16x8 k1 = *(const bf16x8*)((char*)Ks + r1*256 + ((kk*32 + hi*16) ^ ((r1&15)<<4)));
        s0 = __builtin_amdgcn_mfma_f32_32x32x16_bf16(k0, qfB[kk], s0, 0,0,0);
        s1 = __builtin_amdgcn_mfma_f32_32x32x16_bf16(k1, qfB[kk], s1, 0,0,0);
      }
      #pragma unroll
      for (int g=0; g<2; ++g){
        float p[16];
        #pragma unroll
        for (int r=0;r<16;++r){ float sv = g ? s1[r] : s0[r]; p[r] = __builtin_amdgcn_exp2f(sv); lB += p[r]; }
        u32 c0=cvtpk(p[0],p[1]), c1=cvtpk(p[2],p[3]), c2=cvtpk(p[4],p[5]), c3=cvtpk(p[6],p[7]);
        u32 c4=cvtpk(p[8],p[9]), c5=cvtpk(p[10],p[11]), c6=cvtpk(p[12],p[13]), c7=cvtpk(p[14],p[15]);
        pswap(c0,c2); pswap(c1,c3); pswap(c4,c6); pswap(c5,c7);
        paB[g*2+0].w[0]=c0; paB[g*2+0].w[1]=c1; paB[g*2+0].w[2]=c2; paB[g*2+0].w[3]=c3;
        paB[g*2+1].w[0]=c4; paB[g*2+1].w[1]=c5; paB[g*2+1].w[2]=c6; paB[g*2+1].w[3]=c7;
      }
    }
    // ---- PV: each V-frag read feeds both q-blocks (2 MFMA per read) ----
    #pragma unroll
    for (int dg=0;dg<4;++dg){
      int row = dg*32 + l31;
      #pragma unroll
      for (int kvf=0;kvf<4;++kvf){
        bf16x8 vf = *(const bf16x8*)((char*)Vs + row*256 + ((kvf*32 + hi*16) ^ ((row&15)<<4)));
        accA[dg] = __builtin_amdgcn_mfma_f32_32x32x16_bf16(paA[kvf].v, vf, accA[dg], 0,0,0);
        accB[dg] = __builtin_amdgcn_mfma_f32_32x32x16_bf16(paB[kvf].v, vf, accB[dg], 0,0,0);
      }
    }
    __syncthreads();
  }
  float ltA = lA + __shfl_xor(lA, 32, 64);
  float ltB = lB + __shfl_xor(lB, 32, 64);
  if (hi == 0){
    Lp[split*4096 + qbase + l31] = ltA;
    Lp[split*4096 + qbase + 32 + l31] = ltB;
  }
  #pragma unroll
  for (int dg=0;dg<4;++dg){
    #pragma unroll
    for (int r=0;r<16;++r){
      int qo = (r&3) + ((r>>2)<<3) + hi*4;
      Op[((size_t)split*4096 + qbase + qo)*512 + head*128 + dg*32 + l31] = f2b(accA[dg][r]);
      Op[((size_t)split*4096 + qbase + 32 + qo)*512 + head*128 + dg*32 + l31] = f2b(accB[dg][r]);
    }
  }
}

// ---------------- combine bf16 partials (8 splits) -> oatt ----------------
__global__ __launch_bounds__(256) void combine_k(const u16* __restrict__ Op, const float* __restrict__ Lp,
                                                 u16* __restrict__ oatt){
  int idx = blockIdx.x*256 + threadIdx.x;   // 4096*64
  int n = idx >> 6, c8 = (idx & 63) << 3;
  float l = 0.f;
  #pragma unroll
  for (int s=0;s<8;++s) l += Lp[s*4096+n];
  float inv = 1.0f/l;
  float acc[8] = {0,0,0,0,0,0,0,0};
  #pragma unroll
  for (int s=0;s<8;++s){
    bf16x8 v = *(const bf16x8*)(Op + ((size_t)(s*4096+n))*512 + c8);
    #pragma unroll
    for (int j=0;j<8;++j) acc[j] += b2f((u16)v[j]);
  }
  bf16x8 o;
  #pragma unroll
  for (int j=0;j<8;++j) o[j] = (short)f2b(acc[j]*inv);
  *(bf16x8*)(oatt + (size_t)n*512 + c8) = o;
}

// ---------------- launch ----------------
extern "C" void kernel_launch(void* const* d_in, const int* in_sizes, int n_in,
                              void* d_out, int out_size, void* d_ws, size_t ws_size,
                              hipStream_t stream) {
  (void)n_in; (void)out_size; (void)ws_size;
  const float* x    = (const float*)d_in[0];
  const int*   ei   = (const int*)d_in[1];
  const float* W1   = (const float*)d_in[2];
  const float* b1   = (const float*)d_in[3];
  const float* inw  = (const float*)d_in[4];
  const float* inb  = (const float*)d_in[5];
  const float* outw = (const float*)d_in[6];
  const float* outb = (const float*)d_in[7];
  const float* W2   = (const float*)d_in[8];
  const float* b2   = (const float*)d_in[9];
  const float* Wc   = (const float*)d_in[10];
  const float* bc   = (const float*)d_in[11];
  float* out = (float*)d_out;
  const int E = in_sizes[1] / 2;
  const int* srcp = ei;
  const int* dstp = ei + E;

  char* base = (char*)d_ws;
  size_t off = 0;
  auto alloc = [&](size_t bytes)->void*{
    void* p = base + off;
    off = (off + bytes + 255) & ~((size_t)255);
    return p;
  };
  u16* Xb    = (u16*)alloc((size_t)4096*768*2);
  u16* W1T   = (u16*)alloc((size_t)512*768*2);
  u16* inWb  = (u16*)alloc((size_t)1536*512*2);
  u16* outWb = (u16*)alloc((size_t)512*512*2);
  u16* W2T   = (u16*)alloc((size_t)512*512*2);
  u16* WcT   = (u16*)alloc((size_t)32*512*2);
  u16* Hpre  = (u16*)alloc((size_t)4096*512*2);
  u16* h1    = (u16*)alloc((size_t)4096*512*2);
  u16* qkvb  = (u16*)alloc((size_t)4096*1536*2);
  u16* vtg   = (u16*)alloc((size_t)512*4096*2);
  u16* oatt  = (u16*)alloc((size_t)4096*512*2);
  u16* h2    = (u16*)alloc((size_t)4096*512*2);
  u16* h3    = (u16*)alloc((size_t)4096*512*2);
  u16* Opart = (u16*)alloc((size_t)8*4096*512*2);
  float* Lpart = (float*)alloc((size_t)8*4096*4);
  int*   deg  = (int*)alloc(4096*4);
  float* dinv = (float*)alloc(4096*4);
  int*   rowp = (int*)alloc(4097*4);
  int*   curs = (int*)alloc(4096*4);
  int*   srcl = (int*)alloc((size_t)E*4);

  // deg = 0 (stream-ordered; avoids the R3 init/count same-grid race), then fused prep
  hipMemsetAsync(deg, 0, 4096*sizeof(int), stream);
  int degBlocks = (E + 255)/256;
  prep_k<<<4752 + degBlocks, 256, 0, stream>>>(x, inw, outw, W1, W2, Wc, dstp, E,
                                               Xb, inWb, outWb, W1T, W2T, WcT, deg);
  scan_k<<<1,256,0,stream>>>(deg, rowp, curs, dinv);
  scatter_k<<<(E+255)/256,256,0,stream>>>(srcp, dstp, curs, srcl, E);

  // layer 1
  gemm_abt_k<64,64,32,32,false,false,false,true,false><<<dim3(64,8),256,0,stream>>>(Xb, W1T, nullptr, nullptr, nullptr, Hpre, 4096, 512, 768);
  aggregate_k<<<4096,64,0,stream>>>(Hpre, dinv, rowp, srcl, b1, h1);

  // MHA (qkv: 64x128 tile, grid 64x12 = 768 = 3 blocks/CU)
  gemm_abt_k<64,128,32,64,true,false,false,true,true><<<dim3(64,12),256,0,stream>>>(h1, inWb, inb, nullptr, vtg, qkvb, 4096, 1536, 512);
  attn_k<<<dim3(16,4,8),256,0,stream>>>(qkvb, vtg, Opart, Lpart);
  combine_k<<<1024,256,0,stream>>>(Opart, Lpart, oatt);
  gemm_abt_k<64,64,32,32,true,true,false,true,false><<<dim3(64,8),256,0,stream>>>(oatt, outWb, outb, h1, nullptr, h2, 4096, 512, 512);

  // layer 2
  gemm_abt_k<64,64,32,32,false,false,false,true,false><<<dim3(64,8),256,0,stream>>>(h2, W2T, nullptr, nullptr, nullptr, Hpre, 4096, 512, 512);
  aggregate_k<<<4096,64,0,stream>>>(Hpre, dinv, rowp, srcl, b2, h3);

  // classifier -> f32 out
  gemm_abt_k<64,32,16,32,true,false,false,false,false><<<dim3(64,1),256,0,stream>>>(h3, WcT, bc, nullptr, nullptr, out, 4096, 32, 512);
}

// Round 14
// 163.532 us; speedup vs baseline: 1.2945x; 1.0388x over previous
//
#include <hip/hip_runtime.h>

typedef unsigned short u16;
typedef unsigned int u32;
typedef __attribute__((ext_vector_type(8))) short bf16x8;
typedef __attribute__((ext_vector_type(4))) short bf16x4;
typedef __attribute__((ext_vector_type(4))) float f32x4;
typedef __attribute__((ext_vector_type(16))) float f32x16;

__device__ __forceinline__ float b2f(u16 b){ u32 u = ((u32)b)<<16; float f; __builtin_memcpy(&f,&u,4); return f; }
__device__ __forceinline__ u16 f2b(float f){ u32 u; __builtin_memcpy(&u,&f,4); u32 r = (u + 0x7fffu + ((u>>16)&1u)) >> 16; return (u16)r; }
__device__ __forceinline__ u32 cvtpk(float lo, float hi){ u32 r; asm("v_cvt_pk_bf16_f32 %0, %1, %2" : "=v"(r) : "v"(lo), "v"(hi)); return r; }
__device__ __forceinline__ void pswap(u32 &a, u32 &b){ asm("v_permlane32_swap_b32 %0, %1" : "+v"(a), "+v"(b)); }
__device__ __forceinline__ void gload16(const u16* g, u16* l){
  __builtin_amdgcn_global_load_lds((const __attribute__((address_space(1))) void*)g,
                                   (__attribute__((address_space(3))) void*)l, 16, 0, 0);
}

// ---------------- fused prep: converts + weight transposes + degree count ----------------
// deg is zeroed by hipMemsetAsync BEFORE this kernel (init+count in one grid = block race, R3 failure).
__device__ __forceinline__ void conv_body(const float* __restrict__ in, u16* __restrict__ out, int b, int n){
  int i = (b*256 + threadIdx.x)*4;
  if (i + 3 < n){
    float4 v = *(const float4*)(in + i);
    bf16x4 o;
    o[0]=(short)f2b(v.x); o[1]=(short)f2b(v.y); o[2]=(short)f2b(v.z); o[3]=(short)f2b(v.w);
    *(bf16x4*)(out + i) = o;
  } else {
    for (; i<n; ++i) out[i]=f2b(in[i]);
  }
}
__global__ __launch_bounds__(256) void prep_k(const float* __restrict__ x, const float* __restrict__ inw,
    const float* __restrict__ outw, const float* __restrict__ W1, const float* __restrict__ W2,
    const float* __restrict__ Wc, const int* __restrict__ dst, int E,
    u16* __restrict__ Xb, u16* __restrict__ inWb, u16* __restrict__ outWb,
    u16* __restrict__ W1T, u16* __restrict__ W2T, u16* __restrict__ WcT, int* __restrict__ deg){
  __shared__ float tile[32][33];
  int b = blockIdx.x;
  if (b < 3072){ conv_body(x, Xb, b, 4096*768); return; }
  if (b < 3840){ conv_body(inw, inWb, b-3072, 1536*512); return; }
  if (b < 4096){ conv_body(outw, outWb, b-3840, 512*512); return; }
  if (b < 4752){
    const float* in; u16* out; int R, C, bx, by;
    if (b < 4480){ in=W1; out=W1T; R=768; C=512; int lb=b-4096; bx=lb&15; by=lb>>4; }
    else if (b < 4736){ in=W2; out=W2T; R=512; C=512; int lb=b-4480; bx=lb&15; by=lb>>4; }
    else { in=Wc; out=WcT; R=512; C=32; bx=0; by=b-4736; }
    int tx = threadIdx.x & 31, ty = threadIdx.x >> 5;
    int c0 = bx*32, r0 = by*32;
    #pragma unroll
    for (int k=0;k<4;++k){
      int r = r0 + ty + k*8, c = c0 + tx;
      if (r < R && c < C) tile[ty+k*8][tx] = in[(size_t)r*C + c];
    }
    __syncthreads();
    #pragma unroll
    for (int k=0;k<4;++k){
      int c = c0 + ty + k*8, r = r0 + tx;
      if (r < R && c < C) out[(size_t)c*R + r] = f2b(tile[tx][ty+k*8]);
    }
    return;
  }
  int e = (b-4752)*256 + threadIdx.x;
  if (e < E) atomicAdd(&deg[dst[e]], 1);
}

__global__ __launch_bounds__(256) void scan_k(const int* __restrict__ deg, int* __restrict__ row_ptr,
                                              int* __restrict__ cursor, float* __restrict__ dinv){
  __shared__ int lds[256];
  int t = threadIdx.x;
  int base = t*16;
  int cnt[16]; int s = 0;
  #pragma unroll
  for (int k=0;k<16;++k){
    int d = deg[base+k] + 1;      // +1 self-loop (deg holds edge count only)
    cnt[k] = d - 1;
    s += d - 1;
    dinv[base+k] = 1.0f / sqrtf((float)d);
  }
  lds[t] = s; __syncthreads();
  for (int o=1;o<256;o<<=1){
    int v = (t>=o) ? lds[t-o] : 0;
    __syncthreads();
    lds[t] += v;
    __syncthreads();
  }
  int run = lds[t] - s;
  #pragma unroll
  for (int k=0;k<16;++k){ row_ptr[base+k] = run; cursor[base+k] = run; run += cnt[k]; }
  if (t == 255) row_ptr[4096] = run;
}
__global__ __launch_bounds__(256) void scatter_k(const int* __restrict__ src, const int* __restrict__ dst,
                                                 int* __restrict__ cursor, int* __restrict__ srcl, int E){
  int e = blockIdx.x*256 + threadIdx.x;
  if (e < E){
    int d = dst[e];
    int pos = atomicAdd(&cursor[d], 1);
    srcl[pos] = src[e];
  }
}

// ---------------- GCN aggregation: 64 threads/node, bf16x8 (16B/lane) gather, 4-edge ILP ----------------
__global__ __launch_bounds__(64) void aggregate_k(const u16* __restrict__ H, const float* __restrict__ dinv,
                                                  const int* __restrict__ rp, const int* __restrict__ srcl,
                                                  const float* __restrict__ bias, u16* __restrict__ out){
  const int i = blockIdx.x, t = threadIdx.x;
  const float di = dinv[i];
  float a[8];
  {
    bf16x8 hv = *(const bf16x8*)(H + (size_t)i*512 + t*8);
    float wself = di*di;
    #pragma unroll
    for (int j=0;j<8;++j) a[j] = b2f((u16)hv[j])*wself;
  }
  int e0 = rp[i], e1 = rp[i+1];
  int e = e0;
  for (; e+3 < e1; e += 4){
    int s0 = srcl[e], s1 = srcl[e+1], s2 = srcl[e+2], s3 = srcl[e+3];
    float w0 = dinv[s0]*di, w1 = dinv[s1]*di, w2 = dinv[s2]*di, w3 = dinv[s3]*di;
    bf16x8 v0 = *(const bf16x8*)(H + (size_t)s0*512 + t*8);
    bf16x8 v1 = *(const bf16x8*)(H + (size_t)s1*512 + t*8);
    bf16x8 v2 = *(const bf16x8*)(H + (size_t)s2*512 + t*8);
    bf16x8 v3 = *(const bf16x8*)(H + (size_t)s3*512 + t*8);
    #pragma unroll
    for (int j=0;j<8;++j){
      a[j] += b2f((u16)v0[j])*w0 + b2f((u16)v1[j])*w1 + b2f((u16)v2[j])*w2 + b2f((u16)v3[j])*w3;
    }
  }
  for (; e < e1; ++e){
    int s = srcl[e];
    float w = dinv[s]*di;
    bf16x8 v = *(const bf16x8*)(H + (size_t)s*512 + t*8);
    #pragma unroll
    for (int j=0;j<8;++j) a[j] += b2f((u16)v[j])*w;
  }
  bf16x8 o;
  #pragma unroll
  for (int j=0;j<8;++j){
    float v = fmaxf(a[j] + bias[t*8+j], 0.f);
    o[j] = (short)f2b(v);
  }
  *(bf16x8*)(out + (size_t)i*512 + t*8) = o;
}

// ---------------- GEMM: C[M,N] = A[M,K] * B[N,K]^T, global_load_lds staging ----------------
// BM=64 tiles (2+ blocks/CU for N=512 grids); qkv uses BN=128/WN=64 (8 MFMA per 6 frag-reads).
template<int BM,int BN,int WM,int WN,bool BIAS,bool RESID,bool RELU,bool OUTBF,bool QKV>
__global__ __launch_bounds__(256) void gemm_abt_k(
    const u16* __restrict__ A, const u16* __restrict__ B,
    const float* __restrict__ bias, const u16* __restrict__ resid,
    u16* __restrict__ vt, void* __restrict__ Cp, int M, int N, int K)
{
  constexpr int BK = 64;
  constexpr int AISS = (BM*BK)/(256*8);
  constexpr int BISS = (BN*BK)/(256*8);
  constexpr int WC = BN/WN;
  constexpr int FM = WM/16, FN = WN/16;
  constexpr float QS = 0.088388347648318447f * 1.4426950408889634f;  // 1/sqrt(128) * log2(e)
  __shared__ u16 As[BM*BK];
  __shared__ u16 Bs[BN*BK];
  const int tid = threadIdx.x;
  const int wv = tid>>6, ln = tid&63;
  const int l15 = ln&15, l4 = ln>>4;
  const int wm = wv / WC, wn = wv % WC;
  const int bm0 = blockIdx.x*BM, bn0 = blockIdx.y*BN;
  const int arow = tid>>3;
  const int acol = (tid&7)*8;
  f32x4 acc[FM][FN];
  #pragma unroll
  for (int a=0;a<FM;++a)
    #pragma unroll
    for (int b=0;b<FN;++b) acc[a][b] = f32x4{0.f,0.f,0.f,0.f};
  for (int kt=0; kt<K; kt+=BK){
    #pragma unroll
    for (int i=0;i<AISS;++i) gload16(A + (size_t)(bm0 + i*32 + arow)*K + kt + acol, &As[i*2048 + wv*512]);
    #pragma unroll
    for (int i=0;i<BISS;++i) gload16(B + (size_t)(bn0 + i*32 + arow)*K + kt + acol, &Bs[i*2048 + wv*512]);
    __syncthreads();
    #pragma unroll
    for (int kc=0;kc<2;++kc){
      bf16x8 af[FM], bfr[FN];
      #pragma unroll
      for (int a=0;a<FM;++a) af[a] = *(const bf16x8*)(&As[(wm*WM + a*16 + l15)*BK + kc*32 + l4*8]);
      #pragma unroll
      for (int b=0;b<FN;++b) bfr[b] = *(const bf16x8*)(&Bs[(wn*WN + b*16 + l15)*BK + kc*32 + l4*8]);
      #pragma unroll
      for (int a=0;a<FM;++a)
        #pragma unroll
        for (int b=0;b<FN;++b)
          acc[a][b] = __builtin_amdgcn_mfma_f32_16x16x32_bf16(af[a], bfr[b], acc[a][b], 0,0,0);
    }
    __syncthreads();
  }
  #pragma unroll
  for (int a=0;a<FM;++a)
    #pragma unroll
    for (int b=0;b<FN;++b){
      int r0 = bm0 + wm*WM + a*16 + l4*4;
      int c  = bn0 + wn*WN + b*16 + l15;
      if constexpr (QKV){
        float v0 = acc[a][b][0] + bias[c];
        float v1 = acc[a][b][1] + bias[c];
        float v2 = acc[a][b][2] + bias[c];
        float v3 = acc[a][b][3] + bias[c];
        if (c >= 1024){
          bf16x4 pk; pk[0]=(short)f2b(v0); pk[1]=(short)f2b(v1); pk[2]=(short)f2b(v2); pk[3]=(short)f2b(v3);
          *(bf16x4*)(vt + (size_t)(c-1024)*4096 + r0) = pk;
        } else {
          float s = (c < 512) ? QS : 1.0f;
          u16* o = (u16*)Cp;
          o[(size_t)(r0+0)*N + c] = f2b(v0*s);
          o[(size_t)(r0+1)*N + c] = f2b(v1*s);
          o[(size_t)(r0+2)*N + c] = f2b(v2*s);
          o[(size_t)(r0+3)*N + c] = f2b(v3*s);
        }
      } else {
        #pragma unroll
        for (int j=0;j<4;++j){
          int r = r0 + j;
          float v = acc[a][b][j];
          if (BIAS)  v += bias[c];
          if (RESID) v += b2f(resid[(size_t)r*N + c]);
          if (RELU)  v = fmaxf(v, 0.f);
          if (OUTBF) ((u16*)Cp)[(size_t)r*N + c] = f2b(v);
          else       ((float*)Cp)[(size_t)r*N + c] = v;
        }
      }
    }
}

// ---------------- flash attention v6: R11 structure (best measured, 48.9us) + bf16 partials ----------------
// 64 q-rows/wave (448 LDS ops / 512 MFMA ratio), 4-way KV-split, grid (16,4,4)=256, NO launch_bounds
// min-waves (empirical gfx950: (256,N) caps arch VGPR at 256/N -> spill storm; R4/R12).
// Plateau note (R8-R13): attn ~49-52us across {32q,64q}x{1,2,3 blk/CU} -> dependency-chain-bound,
// not LDS-throughput (R11 -30% LDS ops = -3.5%) nor occupancy (extra blocks never helped).
// bf16 partials halve Opart HBM traffic (accuracy proven R6/R9/R13). Vs rows span 256B (bit-7 XOR).
__global__ __launch_bounds__(256) void attn_k(const u16* __restrict__ qkv, const u16* __restrict__ vtg,
                                              u16* __restrict__ Op, float* __restrict__ Lp){
  __shared__ u16 Ks[64*128];    // 64 kv rows x 256B, XOR-swz (row&15)<<4
  __shared__ u16 Vs[128*128];   // 128 d rows x 256B, XOR-swz (row&15)<<4
  const int head = blockIdx.y, split = blockIdx.z;
  const int qbase = blockIdx.x*256 + (threadIdx.x>>6)*64;
  const int tid = threadIdx.x, wv = tid>>6, ln = tid&63;
  const int l31 = ln&31, hi = ln>>5;
  bf16x8 qfA[8], qfB[8];
  {
    const u16* qp = qkv + (size_t)(qbase + l31)*1536 + head*128 + hi*8;
    #pragma unroll
    for (int kk=0;kk<8;++kk){ qfA[kk] = *(const bf16x8*)(qp + kk*16); qfB[kk] = *(const bf16x8*)(qp + 32*1536 + kk*16); }
  }
  f32x16 accA[4], accB[4];
  #pragma unroll
  for (int d=0;d<4;++d)
    #pragma unroll
    for (int r=0;r<16;++r){ accA[d][r] = 0.f; accB[d][r] = 0.f; }
  float lA = 0.f, lB = 0.f;
  const int kR = ln, kG = wv*4;
  const int vR = tid>>1, vG = (tid&1)*4;
  const u16* kbase = qkv + 512 + (size_t)head*128;
  const u16* vbase = vtg + (size_t)(head*128 + vR)*4096;
  const int kv00 = split*1024;
  bf16x8 kreg[4], vreg[4];
  #pragma unroll
  for (int i=0;i<4;++i){
    kreg[i] = *(const bf16x8*)(kbase + (size_t)(kv00 + kR)*1536 + (kG+i)*8);
    vreg[i] = *(const bf16x8*)(vbase + kv00 + (vG+i)*8);
  }
  union PU { u32 w[4]; bf16x8 v; };
  for (int it=0; it<16; ++it){
    #pragma unroll
    for (int i=0;i<4;++i){
      *(bf16x8*)((char*)Ks + kR*256 + (((kG+i)*16) ^ ((kR&15)<<4))) = kreg[i];
      *(bf16x8*)((char*)Vs + vR*256 + (((vG+i)*16) ^ ((vR&15)<<4))) = vreg[i];
    }
    __syncthreads();
    if (it < 15){
      int nb = kv00 + (it+1)*64;
      #pragma unroll
      for (int i=0;i<4;++i){
        kreg[i] = *(const bf16x8*)(kbase + (size_t)(nb + kR)*1536 + (kG+i)*8);
        vreg[i] = *(const bf16x8*)(vbase + nb + (vG+i)*8);
      }
    }
    PU paA[4], paB[4];
    // ---- q-block A: QK^T + softmax ----
    {
      f32x16 s0, s1;
      #pragma unroll
      for (int r=0;r<16;++r){ s0[r]=0.f; s1[r]=0.f; }
      #pragma unroll
      for (int kk=0;kk<8;++kk){
        int r0 = l31, r1 = 32 + l31;
        bf16x8 k0 = *(const bf16x8*)((char*)Ks + r0*256 + ((kk*32 + hi*16) ^ ((r0&15)<<4)));
        bf16x8 k1 = *(const bf16x8*)((char*)Ks + r1*256 + ((kk*32 + hi*16) ^ ((r1&15)<<4)));
        s0 = __builtin_amdgcn_mfma_f32_32x32x16_bf16(k0, qfA[kk], s0, 0,0,0);
        s1 = __builtin_amdgcn_mfma_f32_32x32x16_bf16(k1, qfA[kk], s1, 0,0,0);
      }
      #pragma unroll
      for (int g=0; g<2; ++g){
        float p[16];
        #pragma unroll
        for (int r=0;r<16;++r){ float sv = g ? s1[r] : s0[r]; p[r] = __builtin_amdgcn_exp2f(sv); lA += p[r]; }
        u32 c0=cvtpk(p[0],p[1]), c1=cvtpk(p[2],p[3]), c2=cvtpk(p[4],p[5]), c3=cvtpk(p[6],p[7]);
        u32 c4=cvtpk(p[8],p[9]), c5=cvtpk(p[10],p[11]), c6=cvtpk(p[12],p[13]), c7=cvtpk(p[14],p[15]);
        pswap(c0,c2); pswap(c1,c3); pswap(c4,c6); pswap(c5,c7);
        paA[g*2+0].w[0]=c0; paA[g*2+0].w[1]=c1; paA[g*2+0].w[2]=c2; paA[g*2+0].w[3]=c3;
        paA[g*2+1].w[0]=c4; paA[g*2+1].w[1]=c5; paA[g*2+1].w[2]=c6; paA[g*2+1].w[3]=c7;
      }
    }
    // ---- q-block B: QK^T + softmax (K-frags re-read) ----
    {
      f32x16 s0, s1;
      #pragma unroll
      for (int r=0;r<16;++r){ s0[r]=0.f; s1[r]=0.f; }
      #pragma unroll
      for (int kk=0;kk<8;++kk){
        int r0 = l31, r1 = 32 + l31;
        bf16x8 k0 = *(const bf16x8*)((char*)Ks + r0*256 + ((kk*32 + hi*16) ^ ((r0&15)<<4)));
        bf16x8 k1 = *(const bf16x8*)((char*)Ks + r1*256 + ((kk*32 + hi*16) ^ ((r1&15)<<4)));
        s0 = __builtin_amdgcn_mfma_f32_32x32x16_bf16(k0, qfB[kk], s0, 0,0,0);
        s1 = __builtin_amdgcn_mfma_f32_32x32x16_bf16(k1, qfB[kk], s1, 0,0,0);
      }
      #pragma unroll
      for (int g=0; g<2; ++g){
        float p[16];
        #pragma unroll
        for (int r=0;r<16;++r){ float sv = g ? s1[r] : s0[r]; p[r] = __builtin_amdgcn_exp2f(sv); lB += p[r]; }
        u32 c0=cvtpk(p[0],p[1]), c1=cvtpk(p[2],p[3]), c2=cvtpk(p[4],p[5]), c3=cvtpk(p[6],p[7]);
        u32 c4=cvtpk(p[8],p[9]), c5=cvtpk(p[10],p[11]), c6=cvtpk(p[12],p[13]), c7=cvtpk(p[14],p[15]);
        pswap(c0,c2); pswap(c1,c3); pswap(c4,c6); pswap(c5,c7);
        paB[g*2+0].w[0]=c0; paB[g*2+0].w[1]=c1; paB[g*2+0].w[2]=c2; paB[g*2+0].w[3]=c3;
        paB[g*2+1].w[0]=c4; paB[g*2+1].w[1]=c5; paB[g*2+1].w[2]=c6; paB[g*2+1].w[3]=c7;
      }
    }
    // ---- PV: each V-frag read feeds both q-blocks (2 MFMA per read) ----
    #pragma unroll
    for (int dg=0;dg<4;++dg){
      int row = dg*32 + l31;
      #pragma unroll
      for (int kvf=0;kvf<4;++kvf){
        bf16x8 vf = *(const bf16x8*)((char*)Vs + row*256 + ((kvf*32 + hi*16) ^ ((row&15)<<4)));
        accA[dg] = __builtin_amdgcn_mfma_f32_32x32x16_bf16(paA[kvf].v, vf, accA[dg], 0,0,0);
        accB[dg] = __builtin_amdgcn_mfma_f32_32x32x16_bf16(paB[kvf].v, vf, accB[dg], 0,0,0);
      }
    }
    __syncthreads();
  }
  float ltA = lA + __shfl_xor(lA, 32, 64);
  float ltB = lB + __shfl_xor(lB, 32, 64);
  if (hi == 0){
    Lp[split*4096 + qbase + l31] = ltA;
    Lp[split*4096 + qbase + 32 + l31] = ltB;
  }
  #pragma unroll
  for (int dg=0;dg<4;++dg){
    #pragma unroll
    for (int r=0;r<16;++r){
      int qo = (r&3) + ((r>>2)<<3) + hi*4;
      Op[((size_t)split*4096 + qbase + qo)*512 + head*128 + dg*32 + l31] = f2b(accA[dg][r]);
      Op[((size_t)split*4096 + qbase + 32 + qo)*512 + head*128 + dg*32 + l31] = f2b(accB[dg][r]);
    }
  }
}

// ---------------- combine bf16 partials (4 splits) -> oatt ----------------
__global__ __launch_bounds__(256) void combine_k(const u16* __restrict__ Op, const float* __restrict__ Lp,
                                                 u16* __restrict__ oatt){
  int idx = blockIdx.x*256 + threadIdx.x;   // 4096*64
  int n = idx >> 6, c8 = (idx & 63) << 3;
  float l = Lp[n] + Lp[4096+n] + Lp[8192+n] + Lp[12288+n];
  float inv = 1.0f/l;
  float acc[8] = {0,0,0,0,0,0,0,0};
  #pragma unroll
  for (int s=0;s<4;++s){
    bf16x8 v = *(const bf16x8*)(Op + ((size_t)(s*4096+n))*512 + c8);
    #pragma unroll
    for (int j=0;j<8;++j) acc[j] += b2f((u16)v[j]);
  }
  bf16x8 o;
  #pragma unroll
  for (int j=0;j<8;++j) o[j] = (short)f2b(acc[j]*inv);
  *(bf16x8*)(oatt + (size_t)n*512 + c8) = o;
}

// ---------------- launch ----------------
extern "C" void kernel_launch(void* const* d_in, const int* in_sizes, int n_in,
                              void* d_out, int out_size, void* d_ws, size_t ws_size,
                              hipStream_t stream) {
  (void)n_in; (void)out_size; (void)ws_size;
  const float* x    = (const float*)d_in[0];
  const int*   ei   = (const int*)d_in[1];
  const float* W1   = (const float*)d_in[2];
  const float* b1   = (const float*)d_in[3];
  const float* inw  = (const float*)d_in[4];
  const float* inb  = (const float*)d_in[5];
  const float* outw = (const float*)d_in[6];
  const float* outb = (const float*)d_in[7];
  const float* W2   = (const float*)d_in[8];
  const float* b2   = (const float*)d_in[9];
  const float* Wc   = (const float*)d_in[10];
  const float* bc   = (const float*)d_in[11];
  float* out = (float*)d_out;
  const int E = in_sizes[1] / 2;
  const int* srcp = ei;
  const int* dstp = ei + E;

  char* base = (char*)d_ws;
  size_t off = 0;
  auto alloc = [&](size_t bytes)->void*{
    void* p = base + off;
    off = (off + bytes + 255) & ~((size_t)255);
    return p;
  };
  u16* Xb    = (u16*)alloc((size_t)4096*768*2);
  u16* W1T   = (u16*)alloc((size_t)512*768*2);
  u16* inWb  = (u16*)alloc((size_t)1536*512*2);
  u16* outWb = (u16*)alloc((size_t)512*512*2);
  u16* W2T   = (u16*)alloc((size_t)512*512*2);
  u16* WcT   = (u16*)alloc((size_t)32*512*2);
  u16* Hpre  = (u16*)alloc((size_t)4096*512*2);
  u16* h1    = (u16*)alloc((size_t)4096*512*2);
  u16* qkvb  = (u16*)alloc((size_t)4096*1536*2);
  u16* vtg   = (u16*)alloc((size_t)512*4096*2);
  u16* oatt  = (u16*)alloc((size_t)4096*512*2);
  u16* h2    = (u16*)alloc((size_t)4096*512*2);
  u16* h3    = (u16*)alloc((size_t)4096*512*2);
  u16* Opart = (u16*)alloc((size_t)4*4096*512*2);
  float* Lpart = (float*)alloc((size_t)4*4096*4);
  int*   deg  = (int*)alloc(4096*4);
  float* dinv = (float*)alloc(4096*4);
  int*   rowp = (int*)alloc(4097*4);
  int*   curs = (int*)alloc(4096*4);
  int*   srcl = (int*)alloc((size_t)E*4);

  // deg = 0 (stream-ordered; avoids the R3 init/count same-grid race), then fused prep
  hipMemsetAsync(deg, 0, 4096*sizeof(int), stream);
  int degBlocks = (E + 255)/256;
  prep_k<<<4752 + degBlocks, 256, 0, stream>>>(x, inw, outw, W1, W2, Wc, dstp, E,
                                               Xb, inWb, outWb, W1T, W2T, WcT, deg);
  scan_k<<<1,256,0,stream>>>(deg, rowp, curs, dinv);
  scatter_k<<<(E+255)/256,256,0,stream>>>(srcp, dstp, curs, srcl, E);

  // layer 1
  gemm_abt_k<64,64,32,32,false,false,false,true,false><<<dim3(64,8),256,0,stream>>>(Xb, W1T, nullptr, nullptr, nullptr, Hpre, 4096, 512, 768);
  aggregate_k<<<4096,64,0,stream>>>(Hpre, dinv, rowp, srcl, b1, h1);

  // MHA (qkv: 64x128 tile, grid 64x12 = 768 = 3 blocks/CU)
  gemm_abt_k<64,128,32,64,true,false,false,true,true><<<dim3(64,12),256,0,stream>>>(h1, inWb, inb, nullptr, vtg, qkvb, 4096, 1536, 512);
  attn_k<<<dim3(16,4,4),256,0,stream>>>(qkvb, vtg, Opart, Lpart);
  combine_k<<<1024,256,0,stream>>>(Opart, Lpart, oatt);
  gemm_abt_k<64,64,32,32,true,true,false,true,false><<<dim3(64,8),256,0,stream>>>(oatt, outWb, outb, h1, nullptr, h2, 4096, 512, 512);

  // layer 2
  gemm_abt_k<64,64,32,32,false,false,false,true,false><<<dim3(64,8),256,0,stream>>>(h2, W2T, nullptr, nullptr, nullptr, Hpre, 4096, 512, 512);
  aggregate_k<<<4096,64,0,stream>>>(Hpre, dinv, rowp, srcl, b2, h3);

  // classifier -> f32 out
  gemm_abt_k<64,32,16,32,true,false,false,false,false><<<dim3(64,1),256,0,stream>>>(h3, WcT, bc, nullptr, nullptr, out, 4096, 32, 512);
}

// Round 15
// 163.015 us; speedup vs baseline: 1.2986x; 1.0032x over previous
//
#include <hip/hip_runtime.h>

typedef unsigned short u16;
typedef unsigned int u32;
typedef __attribute__((ext_vector_type(8))) short bf16x8;
typedef __attribute__((ext_vector_type(4))) short bf16x4;
typedef __attribute__((ext_vector_type(4))) float f32x4;
typedef __attribute__((ext_vector_type(16))) float f32x16;

__device__ __forceinline__ float b2f(u16 b){ u32 u = ((u32)b)<<16; float f; __builtin_memcpy(&f,&u,4); return f; }
__device__ __forceinline__ u16 f2b(float f){ u32 u; __builtin_memcpy(&u,&f,4); u32 r = (u + 0x7fffu + ((u>>16)&1u)) >> 16; return (u16)r; }
__device__ __forceinline__ u32 cvtpk(float lo, float hi){ u32 r; asm("v_cvt_pk_bf16_f32 %0, %1, %2" : "=v"(r) : "v"(lo), "v"(hi)); return r; }
__device__ __forceinline__ void pswap(u32 &a, u32 &b){ asm("v_permlane32_swap_b32 %0, %1" : "+v"(a), "+v"(b)); }
__device__ __forceinline__ void gload16(const u16* g, u16* l){
  __builtin_amdgcn_global_load_lds((const __attribute__((address_space(1))) void*)g,
                                   (__attribute__((address_space(3))) void*)l, 16, 0, 0);
}

// ---------------- fused prep: converts (32B/thread) + weight transposes + degree count ----------------
// deg is zeroed by hipMemsetAsync BEFORE this kernel (init+count in one grid = block race, R3 failure).
__device__ __forceinline__ void conv_body8(const float* __restrict__ in, u16* __restrict__ out, int b, int n){
  int i = (b*256 + threadIdx.x)*8;
  if (i + 7 < n){
    float4 v0 = *(const float4*)(in + i);
    float4 v1 = *(const float4*)(in + i + 4);
    bf16x8 o;
    o[0]=(short)f2b(v0.x); o[1]=(short)f2b(v0.y); o[2]=(short)f2b(v0.z); o[3]=(short)f2b(v0.w);
    o[4]=(short)f2b(v1.x); o[5]=(short)f2b(v1.y); o[6]=(short)f2b(v1.z); o[7]=(short)f2b(v1.w);
    *(bf16x8*)(out + i) = o;
  } else {
    for (; i<n; ++i) out[i]=f2b(in[i]);
  }
}
__global__ __launch_bounds__(256) void prep_k(const float* __restrict__ x, const float* __restrict__ inw,
    const float* __restrict__ outw, const float* __restrict__ W1, const float* __restrict__ W2,
    const float* __restrict__ Wc, const int* __restrict__ dst, int E,
    u16* __restrict__ Xb, u16* __restrict__ inWb, u16* __restrict__ outWb,
    u16* __restrict__ W1T, u16* __restrict__ W2T, u16* __restrict__ WcT, int* __restrict__ deg){
  __shared__ float tile[32][33];
  int b = blockIdx.x;
  if (b < 1536){ conv_body8(x, Xb, b, 4096*768); return; }
  if (b < 1920){ conv_body8(inw, inWb, b-1536, 1536*512); return; }
  if (b < 2048){ conv_body8(outw, outWb, b-1920, 512*512); return; }
  if (b < 2704){
    const float* in; u16* out; int R, C, bx, by;
    if (b < 2432){ in=W1; out=W1T; R=768; C=512; int lb=b-2048; bx=lb&15; by=lb>>4; }
    else if (b < 2688){ in=W2; out=W2T; R=512; C=512; int lb=b-2432; bx=lb&15; by=lb>>4; }
    else { in=Wc; out=WcT; R=512; C=32; bx=0; by=b-2688; }
    int tx = threadIdx.x & 31, ty = threadIdx.x >> 5;
    int c0 = bx*32, r0 = by*32;
    #pragma unroll
    for (int k=0;k<4;++k){
      int r = r0 + ty + k*8, c = c0 + tx;
      if (r < R && c < C) tile[ty+k*8][tx] = in[(size_t)r*C + c];
    }
    __syncthreads();
    #pragma unroll
    for (int k=0;k<4;++k){
      int c = c0 + ty + k*8, r = r0 + tx;
      if (r < R && c < C) out[(size_t)c*R + r] = f2b(tile[tx][ty+k*8]);
    }
    return;
  }
  int e = (b-2704)*256 + threadIdx.x;
  if (e < E) atomicAdd(&deg[dst[e]], 1);
}

__global__ __launch_bounds__(256) void scan_k(const int* __restrict__ deg, int* __restrict__ row_ptr,
                                              int* __restrict__ cursor, float* __restrict__ dinv){
  __shared__ int lds[256];
  int t = threadIdx.x;
  int base = t*16;
  int cnt[16]; int s = 0;
  #pragma unroll
  for (int k=0;k<16;++k){
    int d = deg[base+k] + 1;      // +1 self-loop (deg holds edge count only)
    cnt[k] = d - 1;
    s += d - 1;
    dinv[base+k] = 1.0f / sqrtf((float)d);
  }
  lds[t] = s; __syncthreads();
  for (int o=1;o<256;o<<=1){
    int v = (t>=o) ? lds[t-o] : 0;
    __syncthreads();
    lds[t] += v;
    __syncthreads();
  }
  int run = lds[t] - s;
  #pragma unroll
  for (int k=0;k<16;++k){ row_ptr[base+k] = run; cursor[base+k] = run; run += cnt[k]; }
  if (t == 255) row_ptr[4096] = run;
}
__global__ __launch_bounds__(256) void scatter_k(const int* __restrict__ src, const int* __restrict__ dst,
                                                 int* __restrict__ cursor, int* __restrict__ srcl, int E){
  int e = blockIdx.x*256 + threadIdx.x;
  if (e < E){
    int d = dst[e];
    int pos = atomicAdd(&cursor[d], 1);
    srcl[pos] = src[e];
  }
}

// ---------------- GCN aggregation: 64 threads/node, bf16x8 gather, 8-edge ILP ----------------
__global__ __launch_bounds__(64) void aggregate_k(const u16* __restrict__ H, const float* __restrict__ dinv,
                                                  const int* __restrict__ rp, const int* __restrict__ srcl,
                                                  const float* __restrict__ bias, u16* __restrict__ out){
  const int i = blockIdx.x, t = threadIdx.x;
  const float di = dinv[i];
  float a[8];
  {
    bf16x8 hv = *(const bf16x8*)(H + (size_t)i*512 + t*8);
    float wself = di*di;
    #pragma unroll
    for (int j=0;j<8;++j) a[j] = b2f((u16)hv[j])*wself;
  }
  int e0 = rp[i], e1 = rp[i+1];
  int e = e0;
  for (; e+7 < e1; e += 8){
    int s0 = srcl[e],   s1 = srcl[e+1], s2 = srcl[e+2], s3 = srcl[e+3];
    int s4 = srcl[e+4], s5 = srcl[e+5], s6 = srcl[e+6], s7 = srcl[e+7];
    float w0 = dinv[s0]*di, w1 = dinv[s1]*di, w2 = dinv[s2]*di, w3 = dinv[s3]*di;
    float w4 = dinv[s4]*di, w5 = dinv[s5]*di, w6 = dinv[s6]*di, w7 = dinv[s7]*di;
    bf16x8 v0 = *(const bf16x8*)(H + (size_t)s0*512 + t*8);
    bf16x8 v1 = *(const bf16x8*)(H + (size_t)s1*512 + t*8);
    bf16x8 v2 = *(const bf16x8*)(H + (size_t)s2*512 + t*8);
    bf16x8 v3 = *(const bf16x8*)(H + (size_t)s3*512 + t*8);
    bf16x8 v4 = *(const bf16x8*)(H + (size_t)s4*512 + t*8);
    bf16x8 v5 = *(const bf16x8*)(H + (size_t)s5*512 + t*8);
    bf16x8 v6 = *(const bf16x8*)(H + (size_t)s6*512 + t*8);
    bf16x8 v7 = *(const bf16x8*)(H + (size_t)s7*512 + t*8);
    #pragma unroll
    for (int j=0;j<8;++j){
      a[j] += b2f((u16)v0[j])*w0 + b2f((u16)v1[j])*w1 + b2f((u16)v2[j])*w2 + b2f((u16)v3[j])*w3
            + b2f((u16)v4[j])*w4 + b2f((u16)v5[j])*w5 + b2f((u16)v6[j])*w6 + b2f((u16)v7[j])*w7;
    }
  }
  for (; e+3 < e1; e += 4){
    int s0 = srcl[e], s1 = srcl[e+1], s2 = srcl[e+2], s3 = srcl[e+3];
    float w0 = dinv[s0]*di, w1 = dinv[s1]*di, w2 = dinv[s2]*di, w3 = dinv[s3]*di;
    bf16x8 v0 = *(const bf16x8*)(H + (size_t)s0*512 + t*8);
    bf16x8 v1 = *(const bf16x8*)(H + (size_t)s1*512 + t*8);
    bf16x8 v2 = *(const bf16x8*)(H + (size_t)s2*512 + t*8);
    bf16x8 v3 = *(const bf16x8*)(H + (size_t)s3*512 + t*8);
    #pragma unroll
    for (int j=0;j<8;++j){
      a[j] += b2f((u16)v0[j])*w0 + b2f((u16)v1[j])*w1 + b2f((u16)v2[j])*w2 + b2f((u16)v3[j])*w3;
    }
  }
  for (; e < e1; ++e){
    int s = srcl[e];
    float w = dinv[s]*di;
    bf16x8 v = *(const bf16x8*)(H + (size_t)s*512 + t*8);
    #pragma unroll
    for (int j=0;j<8;++j) a[j] += b2f((u16)v[j])*w;
  }
  bf16x8 o;
  #pragma unroll
  for (int j=0;j<8;++j){
    float v = fmaxf(a[j] + bias[t*8+j], 0.f);
    o[j] = (short)f2b(v);
  }
  *(bf16x8*)(out + (size_t)i*512 + t*8) = o;
}

// ---------------- GEMM: C[M,N] = A[M,K] * B[N,K]^T, global_load_lds staging ----------------
// BM=64 tiles (2+ blocks/CU for N=512 grids); qkv uses BN=128/WN=64 (8 MFMA per 6 frag-reads).
template<int BM,int BN,int WM,int WN,bool BIAS,bool RESID,bool RELU,bool OUTBF,bool QKV>
__global__ __launch_bounds__(256) void gemm_abt_k(
    const u16* __restrict__ A, const u16* __restrict__ B,
    const float* __restrict__ bias, const u16* __restrict__ resid,
    u16* __restrict__ vt, void* __restrict__ Cp, int M, int N, int K)
{
  constexpr int BK = 64;
  constexpr int AISS = (BM*BK)/(256*8);
  constexpr int BISS = (BN*BK)/(256*8);
  constexpr int WC = BN/WN;
  constexpr int FM = WM/16, FN = WN/16;
  constexpr float QS = 0.088388347648318447f * 1.4426950408889634f;  // 1/sqrt(128) * log2(e)
  __shared__ u16 As[BM*BK];
  __shared__ u16 Bs[BN*BK];
  const int tid = threadIdx.x;
  const int wv = tid>>6, ln = tid&63;
  const int l15 = ln&15, l4 = ln>>4;
  const int wm = wv / WC, wn = wv % WC;
  const int bm0 = blockIdx.x*BM, bn0 = blockIdx.y*BN;
  const int arow = tid>>3;
  const int acol = (tid&7)*8;
  f32x4 acc[FM][FN];
  #pragma unroll
  for (int a=0;a<FM;++a)
    #pragma unroll
    for (int b=0;b<FN;++b) acc[a][b] = f32x4{0.f,0.f,0.f,0.f};
  for (int kt=0; kt<K; kt+=BK){
    #pragma unroll
    for (int i=0;i<AISS;++i) gload16(A + (size_t)(bm0 + i*32 + arow)*K + kt + acol, &As[i*2048 + wv*512]);
    #pragma unroll
    for (int i=0;i<BISS;++i) gload16(B + (size_t)(bn0 + i*32 + arow)*K + kt + acol, &Bs[i*2048 + wv*512]);
    __syncthreads();
    #pragma unroll
    for (int kc=0;kc<2;++kc){
      bf16x8 af[FM], bfr[FN];
      #pragma unroll
      for (int a=0;a<FM;++a) af[a] = *(const bf16x8*)(&As[(wm*WM + a*16 + l15)*BK + kc*32 + l4*8]);
      #pragma unroll
      for (int b=0;b<FN;++b) bfr[b] = *(const bf16x8*)(&Bs[(wn*WN + b*16 + l15)*BK + kc*32 + l4*8]);
      #pragma unroll
      for (int a=0;a<FM;++a)
        #pragma unroll
        for (int b=0;b<FN;++b)
          acc[a][b] = __builtin_amdgcn_mfma_f32_16x16x32_bf16(af[a], bfr[b], acc[a][b], 0,0,0);
    }
    __syncthreads();
  }
  #pragma unroll
  for (int a=0;a<FM;++a)
    #pragma unroll
    for (int b=0;b<FN;++b){
      int r0 = bm0 + wm*WM + a*16 + l4*4;
      int c  = bn0 + wn*WN + b*16 + l15;
      if constexpr (QKV){
        float v0 = acc[a][b][0] + bias[c];
        float v1 = acc[a][b][1] + bias[c];
        float v2 = acc[a][b][2] + bias[c];
        float v3 = acc[a][b][3] + bias[c];
        if (c >= 1024){
          bf16x4 pk; pk[0]=(short)f2b(v0); pk[1]=(short)f2b(v1); pk[2]=(short)f2b(v2); pk[3]=(short)f2b(v3);
          *(bf16x4*)(vt + (size_t)(c-1024)*4096 + r0) = pk;
        } else {
          float s = (c < 512) ? QS : 1.0f;
          u16* o = (u16*)Cp;
          o[(size_t)(r0+0)*N + c] = f2b(v0*s);
          o[(size_t)(r0+1)*N + c] = f2b(v1*s);
          o[(size_t)(r0+2)*N + c] = f2b(v2*s);
          o[(size_t)(r0+3)*N + c] = f2b(v3*s);
        }
      } else {
        #pragma unroll
        for (int j=0;j<4;++j){
          int r = r0 + j;
          float v = acc[a][b][j];
          if (BIAS)  v += bias[c];
          if (RESID) v += b2f(resid[(size_t)r*N + c]);
          if (RELU)  v = fmaxf(v, 0.f);
          if (OUTBF) ((u16*)Cp)[(size_t)r*N + c] = f2b(v);
          else       ((float*)Cp)[(size_t)r*N + c] = v;
        }
      }
    }
}

// ---------------- flash attention v6 (R14-verified, 47.7us): 64 q-rows/wave, 4-way split, bf16 partials ----------------
// NO launch_bounds min-waves (gfx950 empirical: (256,N) caps arch VGPR at 256/N -> spill; R4/R12).
// Plateau (R8-R13): ~48-52us across all {q-rows}x{blocks/CU} configs -> dependency-chain-bound;
// next lever would be a counted-vmcnt 8-phase rewrite (T3/T4), too race-prone headless.
__global__ __launch_bounds__(256) void attn_k(const u16* __restrict__ qkv, const u16* __restrict__ vtg,
                                              u16* __restrict__ Op, float* __restrict__ Lp){
  __shared__ u16 Ks[64*128];    // 64 kv rows x 256B, XOR-swz (row&15)<<4
  __shared__ u16 Vs[128*128];   // 128 d rows x 256B, XOR-swz (row&15)<<4
  const int head = blockIdx.y, split = blockIdx.z;
  const int qbase = blockIdx.x*256 + (threadIdx.x>>6)*64;
  const int tid = threadIdx.x, wv = tid>>6, ln = tid&63;
  const int l31 = ln&31, hi = ln>>5;
  bf16x8 qfA[8], qfB[8];
  {
    const u16* qp = qkv + (size_t)(qbase + l31)*1536 + head*128 + hi*8;
    #pragma unroll
    for (int kk=0;kk<8;++kk){ qfA[kk] = *(const bf16x8*)(qp + kk*16); qfB[kk] = *(const bf16x8*)(qp + 32*1536 + kk*16); }
  }
  f32x16 accA[4], accB[4];
  #pragma unroll
  for (int d=0;d<4;++d)
    #pragma unroll
    for (int r=0;r<16;++r){ accA[d][r] = 0.f; accB[d][r] = 0.f; }
  float lA = 0.f, lB = 0.f;
  const int kR = ln, kG = wv*4;
  const int vR = tid>>1, vG = (tid&1)*4;
  const u16* kbase = qkv + 512 + (size_t)head*128;
  const u16* vbase = vtg + (size_t)(head*128 + vR)*4096;
  const int kv00 = split*1024;
  bf16x8 kreg[4], vreg[4];
  #pragma unroll
  for (int i=0;i<4;++i){
    kreg[i] = *(const bf16x8*)(kbase + (size_t)(kv00 + kR)*1536 + (kG+i)*8);
    vreg[i] = *(const bf16x8*)(vbase + kv00 + (vG+i)*8);
  }
  union PU { u32 w[4]; bf16x8 v; };
  for (int it=0; it<16; ++it){
    #pragma unroll
    for (int i=0;i<4;++i){
      *(bf16x8*)((char*)Ks + kR*256 + (((kG+i)*16) ^ ((kR&15)<<4))) = kreg[i];
      *(bf16x8*)((char*)Vs + vR*256 + (((vG+i)*16) ^ ((vR&15)<<4))) = vreg[i];
    }
    __syncthreads();
    if (it < 15){
      int nb = kv00 + (it+1)*64;
      #pragma unroll
      for (int i=0;i<4;++i){
        kreg[i] = *(const bf16x8*)(kbase + (size_t)(nb + kR)*1536 + (kG+i)*8);
        vreg[i] = *(const bf16x8*)(vbase + nb + (vG+i)*8);
      }
    }
    PU paA[4], paB[4];
    // ---- q-block A: QK^T + softmax ----
    {
      f32x16 s0, s1;
      #pragma unroll
      for (int r=0;r<16;++r){ s0[r]=0.f; s1[r]=0.f; }
      #pragma unroll
      for (int kk=0;kk<8;++kk){
        int r0 = l31, r1 = 32 + l31;
        bf16x8 k0 = *(const bf16x8*)((char*)Ks + r0*256 + ((kk*32 + hi*16) ^ ((r0&15)<<4)));
        bf16x8 k1 = *(const bf16x8*)((char*)Ks + r1*256 + ((kk*32 + hi*16) ^ ((r1&15)<<4)));
        s0 = __builtin_amdgcn_mfma_f32_32x32x16_bf16(k0, qfA[kk], s0, 0,0,0);
        s1 = __builtin_amdgcn_mfma_f32_32x32x16_bf16(k1, qfA[kk], s1, 0,0,0);
      }
      #pragma unroll
      for (int g=0; g<2; ++g){
        float p[16];
        #pragma unroll
        for (int r=0;r<16;++r){ float sv = g ? s1[r] : s0[r]; p[r] = __builtin_amdgcn_exp2f(sv); lA += p[r]; }
        u32 c0=cvtpk(p[0],p[1]), c1=cvtpk(p[2],p[3]), c2=cvtpk(p[4],p[5]), c3=cvtpk(p[6],p[7]);
        u32 c4=cvtpk(p[8],p[9]), c5=cvtpk(p[10],p[11]), c6=cvtpk(p[12],p[13]), c7=cvtpk(p[14],p[15]);
        pswap(c0,c2); pswap(c1,c3); pswap(c4,c6); pswap(c5,c7);
        paA[g*2+0].w[0]=c0; paA[g*2+0].w[1]=c1; paA[g*2+0].w[2]=c2; paA[g*2+0].w[3]=c3;
        paA[g*2+1].w[0]=c4; paA[g*2+1].w[1]=c5; paA[g*2+1].w[2]=c6; paA[g*2+1].w[3]=c7;
      }
    }
    // ---- q-block B: QK^T + softmax (K-frags re-read) ----
    {
      f32x16 s0, s1;
      #pragma unroll
      for (int r=0;r<16;++r){ s0[r]=0.f; s1[r]=0.f; }
      #pragma unroll
      for (int kk=0;kk<8;++kk){
        int r0 = l31, r1 = 32 + l31;
        bf16x8 k0 = *(const bf16x8*)((char*)Ks + r0*256 + ((kk*32 + hi*16) ^ ((r0&15)<<4)));
        bf16x8 k1 = *(const bf16x8*)((char*)Ks + r1*256 + ((kk*32 + hi*16) ^ ((r1&15)<<4)));
        s0 = __builtin_amdgcn_mfma_f32_32x32x16_bf16(k0, qfB[kk], s0, 0,0,0);
        s1 = __builtin_amdgcn_mfma_f32_32x32x16_bf16(k1, qfB[kk], s1, 0,0,0);
      }
      #pragma unroll
      for (int g=0; g<2; ++g){
        float p[16];
        #pragma unroll
        for (int r=0;r<16;++r){ float sv = g ? s1[r] : s0[r]; p[r] = __builtin_amdgcn_exp2f(sv); lB += p[r]; }
        u32 c0=cvtpk(p[0],p[1]), c1=cvtpk(p[2],p[3]), c2=cvtpk(p[4],p[5]), c3=cvtpk(p[6],p[7]);
        u32 c4=cvtpk(p[8],p[9]), c5=cvtpk(p[10],p[11]), c6=cvtpk(p[12],p[13]), c7=cvtpk(p[14],p[15]);
        pswap(c0,c2); pswap(c1,c3); pswap(c4,c6); pswap(c5,c7);
        paB[g*2+0].w[0]=c0; paB[g*2+0].w[1]=c1; paB[g*2+0].w[2]=c2; paB[g*2+0].w[3]=c3;
        paB[g*2+1].w[0]=c4; paB[g*2+1].w[1]=c5; paB[g*2+1].w[2]=c6; paB[g*2+1].w[3]=c7;
      }
    }
    // ---- PV: each V-frag read feeds both q-blocks (2 MFMA per read) ----
    #pragma unroll
    for (int dg=0;dg<4;++dg){
      int row = dg*32 + l31;
      #pragma unroll
      for (int kvf=0;kvf<4;++kvf){
        bf16x8 vf = *(const bf16x8*)((char*)Vs + row*256 + ((kvf*32 + hi*16) ^ ((row&15)<<4)));
        accA[dg] = __builtin_amdgcn_mfma_f32_32x32x16_bf16(paA[kvf].v, vf, accA[dg], 0,0,0);
        accB[dg] = __builtin_amdgcn_mfma_f32_32x32x16_bf16(paB[kvf].v, vf, accB[dg], 0,0,0);
      }
    }
    __syncthreads();
  }
  float ltA = lA + __shfl_xor(lA, 32, 64);
  float ltB = lB + __shfl_xor(lB, 32, 64);
  if (hi == 0){
    Lp[split*4096 + qbase + l31] = ltA;
    Lp[split*4096 + qbase + 32 + l31] = ltB;
  }
  #pragma unroll
  for (int dg=0;dg<4;++dg){
    #pragma unroll
    for (int r=0;r<16;++r){
      int qo = (r&3) + ((r>>2)<<3) + hi*4;
      Op[((size_t)split*4096 + qbase + qo)*512 + head*128 + dg*32 + l31] = f2b(accA[dg][r]);
      Op[((size_t)split*4096 + qbase + 32 + qo)*512 + head*128 + dg*32 + l31] = f2b(accB[dg][r]);
    }
  }
}

// ---------------- combine bf16 partials (4 splits) -> oatt ----------------
__global__ __launch_bounds__(256) void combine_k(const u16* __restrict__ Op, const float* __restrict__ Lp,
                                                 u16* __restrict__ oatt){
  int idx = blockIdx.x*256 + threadIdx.x;   // 4096*64
  int n = idx >> 6, c8 = (idx & 63) << 3;
  float l = Lp[n] + Lp[4096+n] + Lp[8192+n] + Lp[12288+n];
  float inv = 1.0f/l;
  float acc[8] = {0,0,0,0,0,0,0,0};
  #pragma unroll
  for (int s=0;s<4;++s){
    bf16x8 v = *(const bf16x8*)(Op + ((size_t)(s*4096+n))*512 + c8);
    #pragma unroll
    for (int j=0;j<8;++j) acc[j] += b2f((u16)v[j]);
  }
  bf16x8 o;
  #pragma unroll
  for (int j=0;j<8;++j) o[j] = (short)f2b(acc[j]*inv);
  *(bf16x8*)(oatt + (size_t)n*512 + c8) = o;
}

// ---------------- launch ----------------
extern "C" void kernel_launch(void* const* d_in, const int* in_sizes, int n_in,
                              void* d_out, int out_size, void* d_ws, size_t ws_size,
                              hipStream_t stream) {
  (void)n_in; (void)out_size; (void)ws_size;
  const float* x    = (const float*)d_in[0];
  const int*   ei   = (const int*)d_in[1];
  const float* W1   = (const float*)d_in[2];
  const float* b1   = (const float*)d_in[3];
  const float* inw  = (const float*)d_in[4];
  const float* inb  = (const float*)d_in[5];
  const float* outw = (const float*)d_in[6];
  const float* outb = (const float*)d_in[7];
  const float* W2   = (const float*)d_in[8];
  const float* b2   = (const float*)d_in[9];
  const float* Wc   = (const float*)d_in[10];
  const float* bc   = (const float*)d_in[11];
  float* out = (float*)d_out;
  const int E = in_sizes[1] / 2;
  const int* srcp = ei;
  const int* dstp = ei + E;

  char* base = (char*)d_ws;
  size_t off = 0;
  auto alloc = [&](size_t bytes)->void*{
    void* p = base + off;
    off = (off + bytes + 255) & ~((size_t)255);
    return p;
  };
  u16* Xb    = (u16*)alloc((size_t)4096*768*2);
  u16* W1T   = (u16*)alloc((size_t)512*768*2);
  u16* inWb  = (u16*)alloc((size_t)1536*512*2);
  u16* outWb = (u16*)alloc((size_t)512*512*2);
  u16* W2T   = (u16*)alloc((size_t)512*512*2);
  u16* WcT   = (u16*)alloc((size_t)32*512*2);
  u16* Hpre  = (u16*)alloc((size_t)4096*512*2);
  u16* h1    = (u16*)alloc((size_t)4096*512*2);
  u16* qkvb  = (u16*)alloc((size_t)4096*1536*2);
  u16* vtg   = (u16*)alloc((size_t)512*4096*2);
  u16* oatt  = (u16*)alloc((size_t)4096*512*2);
  u16* h2    = (u16*)alloc((size_t)4096*512*2);
  u16* h3    = (u16*)alloc((size_t)4096*512*2);
  u16* Opart = (u16*)alloc((size_t)4*4096*512*2);
  float* Lpart = (float*)alloc((size_t)4*4096*4);
  int*   deg  = (int*)alloc(4096*4);
  float* dinv = (float*)alloc(4096*4);
  int*   rowp = (int*)alloc(4097*4);
  int*   curs = (int*)alloc(4096*4);
  int*   srcl = (int*)alloc((size_t)E*4);

  // deg = 0 (stream-ordered; avoids the R3 init/count same-grid race), then fused prep
  hipMemsetAsync(deg, 0, 4096*sizeof(int), stream);
  int degBlocks = (E + 255)/256;
  prep_k<<<2704 + degBlocks, 256, 0, stream>>>(x, inw, outw, W1, W2, Wc, dstp, E,
                                               Xb, inWb, outWb, W1T, W2T, WcT, deg);
  scan_k<<<1,256,0,stream>>>(deg, rowp, curs, dinv);
  scatter_k<<<(E+255)/256,256,0,stream>>>(srcp, dstp, curs, srcl, E);

  // layer 1
  gemm_abt_k<64,64,32,32,false,false,false,true,false><<<dim3(64,8),256,0,stream>>>(Xb, W1T, nullptr, nullptr, nullptr, Hpre, 4096, 512, 768);
  aggregate_k<<<4096,64,0,stream>>>(Hpre, dinv, rowp, srcl, b1, h1);

  // MHA (qkv: 64x128 tile, grid 64x12 = 768 = 3 blocks/CU)
  gemm_abt_k<64,128,32,64,true,false,false,true,true><<<dim3(64,12),256,0,stream>>>(h1, inWb, inb, nullptr, vtg, qkvb, 4096, 1536, 512);
  attn_k<<<dim3(16,4,4),256,0,stream>>>(qkvb, vtg, Opart, Lpart);
  combine_k<<<1024,256,0,stream>>>(Opart, Lpart, oatt);
  gemm_abt_k<64,64,32,32,true,true,false,true,false><<<dim3(64,8),256,0,stream>>>(oatt, outWb, outb, h1, nullptr, h2, 4096, 512, 512);

  // layer 2
  gemm_abt_k<64,64,32,32,false,false,false,true,false><<<dim3(64,8),256,0,stream>>>(h2, W2T, nullptr, nullptr, nullptr, Hpre, 4096, 512, 512);
  aggregate_k<<<4096,64,0,stream>>>(Hpre, dinv, rowp, srcl, b2, h3);

  // classifier -> f32 out
  gemm_abt_k<64,32,16,32,true,false,false,false,false><<<dim3(64,1),256,0,stream>>>(h3, WcT, bc, nullptr, nullptr, out, 4096, 32, 512);
}